// Round 3
// baseline (4741.746 us; speedup 1.0000x reference)
//
#include <hip/hip_runtime.h>
#include <hip/hip_bf16.h>

// Problem constants: C=256 channels, equirect H=256 x W=512, faces 256x256.
// Padded NHWC conv-input layout: Xp[(H+2)=258 rows][(W+2)=514 cols][256 ch] bf16.
#define NPIX 131072        // 256*512
#define WP   514
#define XP_BYTES 67897344  // 258*514*256*2
#define XP_STRIDE 67962880 // XP_BYTES + 64KB slack (conv halo staging over-reads up to 7KB)
#define FT_BYTES 100663296 // 3 faces * 65536 px * 256 ch * 2B (NHWC bf16)

typedef __attribute__((ext_vector_type(8))) short bf16x8;  // 8 bf16 = 4 VGPRs
typedef __attribute__((ext_vector_type(4))) float f32x4;

typedef const __attribute__((address_space(1))) void g_cvoid;
typedef __attribute__((address_space(3))) void l_void;

__device__ __forceinline__ void async16(const void* g, void* l) {
  // width-16 global->LDS DMA; LDS dest = wave-uniform base + lane*16
  __builtin_amdgcn_global_load_lds((g_cvoid*)g, (l_void*)l, 16, 0, 0);
}

// ---------------- ws state init (ws is re-poisoned 0xAA before every launch) ---
__global__ void zero_borders(__hip_bfloat16* Xm, __hip_bfloat16* Xa) {
  int i = blockIdx.x;  // 0..1539 border pixels
  __hip_bfloat16* X = blockIdx.y ? Xa : Xm;
  long ppix;
  if (i < 514)       ppix = i;                                  // top row
  else if (i < 1028) ppix = 257L * WP + (i - 514);              // bottom row
  else if (i < 1284) ppix = (long)(i - 1028 + 1) * WP;          // left col
  else               ppix = (long)(i - 1284 + 1) * WP + 513;    // right col
  ((unsigned int*)(X + ppix * 256))[threadIdx.x] = 0u;          // 128 u32 = 256 bf16
}

__global__ void zero_mask(float* maskacc) {
  maskacc[blockIdx.x * 256 + threadIdx.x] = 0.f;
}

// Wf [cout][cin][3][3] fp32 -> Wtt [(o*32 + ci>>3)][cout][ci&7] bf16
// so a B fragment (quad lq, lane ln) reads 256B-contiguous, coalesced b128.
__global__ void prep_weights(const float* __restrict__ Wf, __hip_bfloat16* __restrict__ Wtt) {
  int idx = blockIdx.x * 256 + threadIdx.x;   // 589824 total
  int cout = idx / 2304, rem = idx % 2304;
  int o = rem >> 8, ci = rem & 255;
  Wtt[(((o << 5) + (ci >> 3)) << 11) + (cout << 3) + (ci & 7)] =
      __float2bfloat16(Wf[(cout * 256 + ci) * 9 + o]);
}

// ---------------- m (NCHW fp32) -> padded NHWC bf16 ----------------------------
__global__ void nchw_to_pad_nhwc(const float* __restrict__ src, __hip_bfloat16* __restrict__ Xp) {
  __shared__ __align__(16) __hip_bfloat16 tile[64 * 264];  // 64 px x 256 ch (+8 pad)
  int tid = threadIdx.x;
  int p0 = blockIdx.x * 64;
  int px = tid & 63, w = tid >> 6;
  for (int k = 0; k < 64; ++k) {
    int c = (k << 2) + w;
    tile[px * 264 + c] = __float2bfloat16(src[(long)c * NPIX + p0 + px]);
  }
  __syncthreads();
  int y = p0 >> 9, x0 = p0 & 511;
  long basep = (long)(y + 1) * WP + x0 + 1;
  for (int pass = 0; pass < 8; ++pass) {
    int tpx = (pass << 3) + (tid >> 5);
    int chunk = tid & 31;
    uint4 v = *(const uint4*)&tile[tpx * 264 + (chunk << 3)];
    *(uint4*)&Xp[(basep + tpx) * 256 + (chunk << 3)] = v;
  }
}

// ---------------- faces (NCHW fp32, 3 used faces) -> NHWC bf16 -----------------
__global__ void face_to_nhwc(const float* __restrict__ fb, const float* __restrict__ fd,
                             const float* __restrict__ fu, __hip_bfloat16* __restrict__ Ft) {
  __shared__ __align__(16) __hip_bfloat16 tile[64 * 264];
  int tid = threadIdx.x;
  int face = blockIdx.x >> 10;         // 0..2 (slot: 0=b,1=d,2=u)
  int p0 = (blockIdx.x & 1023) << 6;
  const float* src = (face == 0) ? fb : (face == 1) ? fd : fu;
  int px = tid & 63, w = tid >> 6;
  for (int k = 0; k < 64; ++k) {
    int c = (k << 2) + w;
    tile[px * 264 + c] = __float2bfloat16(src[(long)c * 65536 + p0 + px]);
  }
  __syncthreads();
  long basep = ((long)face << 16) + p0;
  for (int pass = 0; pass < 8; ++pass) {
    int tpx = (pass << 3) + (tid >> 5);
    int chunk = tid & 31;
    uint4 v = *(const uint4*)&tile[tpx * 264 + (chunk << 3)];
    *(uint4*)&Ft[((basep + tpx) << 8) + (chunk << 3)] = v;
  }
}

// ---------------- cube2equi sampling v2: one wave per output pixel -------------
// Ft is NHWC bf16: sample = 512B contiguous. Lane parity = u0/u1, lane>>1 = ch octet.
__device__ __forceinline__ void bf8_fma(uint4 q, float w, float* acc) {
  unsigned x;
  x = q.x; acc[0] += w * __uint_as_float(x << 16); acc[1] += w * __uint_as_float(x & 0xffff0000u);
  x = q.y; acc[2] += w * __uint_as_float(x << 16); acc[3] += w * __uint_as_float(x & 0xffff0000u);
  x = q.z; acc[4] += w * __uint_as_float(x << 16); acc[5] += w * __uint_as_float(x & 0xffff0000u);
  x = q.w; acc[6] += w * __uint_as_float(x << 16); acc[7] += w * __uint_as_float(x & 0xffff0000u);
}

__global__ void aux_gen_v2(const __hip_bfloat16* __restrict__ Ft,
                           __hip_bfloat16* __restrict__ Xp) {
  const int lane = threadIdx.x & 63;
  const int p = (blockIdx.x << 2) + (threadIdx.x >> 6);  // one wave per pixel
  const int yy = p >> 9, xx = p & 511;

  // geometry (wave-uniform; fast HW trig: v_sin/v_cos, ~2^-20 rel err vs 0.11 tol)
  float theta = ((xx + 0.5f) / 512.f) * 6.283185307179586f - 3.141592653589793f;
  float phi   = 1.5707963267948966f - ((yy + 0.5f) / 256.f) * 3.141592653589793f;
  float st = __sinf(theta), ct = __cosf(theta);
  float sp = __sinf(phi),   cp = __cosf(phi);
  float dx = cp * st, dy = sp, dz = cp * ct;
  float ax = fabsf(dx), ay = fabsf(dy), az = fabsf(dz);
  float mx = fmaxf(fmaxf(ax, ay), az);
  float pxn = dx / mx, pyn = dy / mx, pzn = dz / mx;
  bool cz = (az >= ax) && (az >= ay);
  bool cx = (!cz) && (ax >= ay);
  int face; float a, b;
  if (cz)      { face = dz > 0.f ? 2 : 0; a = dz > 0.f ? pxn : -pxn; b = -pyn; }
  else if (cx) { face = dx > 0.f ? 4 : 3; a = dx > 0.f ? -pzn : pzn; b = -pyn; }
  else         { face = dy > 0.f ? 5 : 1; a = pxn; b = dy > 0.f ? pzn : -pzn; }
  float uu = fminf(fmaxf((a + 1.f) * 0.5f * 255.f, 0.f), 255.f);
  float vv = fminf(fmaxf((b + 1.f) * 0.5f * 255.f, 0.f), 255.f);

  const long outbase = ((long)((yy + 1) * WP + xx + 1)) << 8;
  const int c0 = (lane >> 1) << 3;     // channel octet
  const int up = lane & 1;             // 0 -> u0, 1 -> u1
  const int slot = (face == 0) ? 0 : (face == 1) ? 1 : (face == 5) ? 2 : -1;

  if (slot < 0) {                      // faces 2/3/4 are the zero 'emptyFace'
    if (!up) *(uint4*)&Xp[outbase + c0] = make_uint4(0u, 0u, 0u, 0u);
    return;
  }
  int u0 = (int)uu, v0 = (int)vv;
  int u1 = min(u0 + 1, 255), v1 = min(v0 + 1, 255);
  float wu = uu - (float)u0, wv = vv - (float)v0;
  int uc = up ? u1 : u0;
  float wA = up ? wu : (1.f - wu);
  const __hip_bfloat16* base = Ft + ((long)slot << 24);  // slot * 65536 * 256

  float acc[8] = {0.f, 0.f, 0.f, 0.f, 0.f, 0.f, 0.f, 0.f};
  uint4 q0 = *(const uint4*)&base[(((long)(v0 << 8) + uc) << 8) + c0];
  uint4 q1 = *(const uint4*)&base[(((long)(v1 << 8) + uc) << 8) + c0];
  bf8_fma(q0, (1.f - wv) * wA, acc);
  bf8_fma(q1, wv * wA, acc);
#pragma unroll
  for (int j = 0; j < 8; ++j) acc[j] += __shfl_xor(acc[j], 1);
  if (!up) {
    union { uint4 q; __hip_bfloat16 h[8]; } o;
#pragma unroll
    for (int j = 0; j < 8; ++j) o.h[j] = __float2bfloat16(acc[j]);
    *(uint4*)&Xp[outbase + c0] = o.q;
  }
}

// ---------------- cube2equi v1 (fallback when ws too small for Ft) -------------
__global__ void aux_gen(const float* __restrict__ fb, const float* __restrict__ fd,
                        const float* __restrict__ fu,
                        __hip_bfloat16* __restrict__ Xp) {
  __shared__ __align__(16) __hip_bfloat16 tile[64 * 264];
  int tid = threadIdx.x;
  int p0 = blockIdx.x * 64;
  int px = tid & 63, w = tid >> 6;

  int p = p0 + px;
  int yy = p >> 9, xx = p & 511;
  float theta = ((xx + 0.5f) / 512.f) * 6.283185307179586f - 3.141592653589793f;
  float phi   = 1.5707963267948966f - ((yy + 0.5f) / 256.f) * 3.141592653589793f;
  float st = __sinf(theta), ct = __cosf(theta);
  float sp = __sinf(phi),   cp = __cosf(phi);
  float dx = cp * st, dy = sp, dz = cp * ct;
  float ax = fabsf(dx), ay = fabsf(dy), az = fabsf(dz);
  float mx = fmaxf(fmaxf(ax, ay), az);
  float pxn = dx / mx, pyn = dy / mx, pzn = dz / mx;
  bool cz = (az >= ax) && (az >= ay);
  bool cx = (!cz) && (ax >= ay);
  int face; float a, b;
  if (cz)      { face = dz > 0.f ? 2 : 0; a = dz > 0.f ? pxn : -pxn; b = -pyn; }
  else if (cx) { face = dx > 0.f ? 4 : 3; a = dx > 0.f ? -pzn : pzn; b = -pyn; }
  else         { face = dy > 0.f ? 5 : 1; a = pxn; b = dy > 0.f ? pzn : -pzn; }
  float uu = fminf(fmaxf((a + 1.f) * 0.5f * 255.f, 0.f), 255.f);
  float vv = fminf(fmaxf((b + 1.f) * 0.5f * 255.f, 0.f), 255.f);

  const float* F = (face == 0) ? fb : (face == 1) ? fd : (face == 5) ? fu : nullptr;
  int u0 = (int)uu, v0 = (int)vv;
  int u1 = min(u0 + 1, 255), v1 = min(v0 + 1, 255);
  float wu = uu - (float)u0, wv = vv - (float)v0;
  float w00 = (1.f - wv) * (1.f - wu), w01 = (1.f - wv) * wu;
  float w10 = wv * (1.f - wu),         w11 = wv * wu;
  int i00 = v0 * 256 + u0, i01 = v0 * 256 + u1;
  int i10 = v1 * 256 + u0, i11 = v1 * 256 + u1;
  for (int k = 0; k < 64; ++k) {
    int c = (k << 2) + w;
    float val = 0.f;
    if (F) {
      const float* Fc = F + ((long)c << 16);
      val = w00 * Fc[i00] + w01 * Fc[i01] + w10 * Fc[i10] + w11 * Fc[i11];
    }
    tile[px * 264 + c] = __float2bfloat16(val);
  }
  __syncthreads();
  int y = p0 >> 9, x0g = p0 & 511;
  long basep = (long)(y + 1) * WP + x0g + 1;
  for (int pass = 0; pass < 8; ++pass) {
    int tpx = (pass << 3) + (tid >> 5);
    int chunk = tid & 31;
    uint4 v = *(const uint4*)&tile[tpx * 264 + (chunk << 3)];
    *(uint4*)&Xp[(basep + tpx) * 256 + (chunk << 3)] = v;
  }
}

// ---------------- 3x3 conv as implicit GEMM (MFMA bf16) ------------------------
// v5 (on the PROVEN round-2 two-barrier-per-slice template; round 1's
// single-barrier pipeline raced and stays reverted):
//  - BK=64: 4 ci-slices of 64 ch (was 8x32) -> barriers 16 -> 8, 2x MFMA
//    per staging phase (288/wave) amortizes each vmcnt(0) drain.
//  - T2 XOR swizzle, both-sides (rule #21): LDS phys slot = quad ^ (px&7)
//    within each 128B pixel-row. Staging pre-swizzles the GLOBAL source
//    (lane l fetches quad (l&7)^(l>>3)); reads XOR the slot with px&7.
//    Kills the 8-way bank conflict of the old 64B-row layout (lanes now
//    spread uniformly over all 8 bank groups).
//  - B (Wtt) fragments software-pipelined one tap ahead; launch_bounds
//    (512,8) caps unified regs at 256 (est ~140 VGPR + 64 AGPR) so the
//    compiler has room to hide per-tap L2 latency (VGPR=64 couldn't).
// grid = dim3(1024, 2): y==0 -> aux conv (stores MauxT), y==1 -> main conv.
// XCD strip swizzle: 1024 % 8 == 0 -> bijective.
__global__ __launch_bounds__(512, 8)
void conv3x3_mfma(const __hip_bfloat16* __restrict__ Xpa,
                  const __hip_bfloat16* __restrict__ Xpm,
                  const __hip_bfloat16* __restrict__ Wtt,
                  const float* __restrict__ bias,
                  const float* __restrict__ wm,
                  __hip_bfloat16* __restrict__ Out,
                  float* __restrict__ maskacc) {
  __shared__ __align__(16) __hip_bfloat16 At[4 * 80 * 64];   // 40960 B halo (4 rows x 80 px x 64 ch)
  const int tid = threadIdx.x;
  const int wave = tid >> 6, lane = tid & 63;
  const bool aux = (blockIdx.y == 0);
  const __hip_bfloat16* __restrict__ Xp = aux ? Xpa : Xpm;
  const float* __restrict__ wmv = aux ? wm + 256 : wm;

  const int tile = ((blockIdx.x & 7) << 7) + (blockIdx.x >> 3);  // strip -> XCD
  const int x0 = (tile >> 7) << 6;     // col strip (8 strips of 64)
  const int y0 = (tile & 127) << 1;    // row pair (rows vary fastest per XCD)
  const int wrow = wave >> 2;          // this wave's pixel row within tile (0/1)
  const int n_off = (wave & 3) << 6;   // this wave's cout quarter (0/64/128/192)
  const int lq = lane >> 4, ln = lane & 15;

  // halo staging: wave pair (srow = wave>>1) stages padded row (y0 + srow);
  // even wave covers 8-px chunks {0,8,16,24,32}, odd {40,48,56,64,72}.
  // One async16 = 8 px x 8 ci-quads; lane l -> px offset l>>3, LDS slot l&7.
  // Swizzle: lane fetches GLOBAL quad (l&7)^(l>>3) so LDS slot s of pixel p
  // holds logical quad s^(p&7)  (chunks and srow*80 are both = 0 mod 8).
  const int srow = wave >> 1;
  const long stage_row = (long)(y0 + srow) * WP + x0;
  const int q_px = lane >> 3;                     // 0..7 pixel offset in chunk
  const int q_ci = ((lane & 7) ^ q_px) << 3;      // swizzled ci offset 0..56

  f32x4 acc[4][4] = {};   // [mi (16-px col group)][ni (16-cout group)]

  for (int s = 0; s < 4; ++s) {
    const int ci0 = s << 6;
#pragma unroll
    for (int j = 0; j < 5; ++j) {
      const int chunk = ((wave & 1) ? 40 : 0) + (j << 3);
      async16(Xp + ((stage_row + chunk + q_px) << 8) + ci0 + q_ci,
              &At[(srow * 80 + chunk) << 6]);
    }
    __syncthreads();   // drains vmcnt -> staged halo visible to all waves

    // B fragments for tap 0 (both kk halves), then pipeline one tap ahead
    bf16x8 bcur[2][4];
#pragma unroll
    for (int kk = 0; kk < 2; ++kk)
#pragma unroll
      for (int ni = 0; ni < 4; ++ni)
        bcur[kk][ni] = *(const bf16x8*)&Wtt[(((0 << 5) + (s << 3) + (kk << 2) + lq) << 11) +
                                            ((n_off + ni * 16 + ln) << 3)];
#pragma unroll
    for (int o = 0; o < 9; ++o) {
      bf16x8 bnext[2][4];
      if (o < 8) {
#pragma unroll
        for (int kk = 0; kk < 2; ++kk)
#pragma unroll
          for (int ni = 0; ni < 4; ++ni)
            bnext[kk][ni] = *(const bf16x8*)&Wtt[((((o + 1) << 5) + (s << 3) + (kk << 2) + lq) << 11) +
                                                 ((n_off + ni * 16 + ln) << 3)];
      }
      const int dy = o / 3, dxo = o % 3;
      const int arow = (wrow + dy) * 80;
      bf16x8 af[2][4];
#pragma unroll
      for (int mi = 0; mi < 4; ++mi) {
        const int px = arow + mi * 16 + ln + dxo;       // arow = 0 mod 8
        const int sw = px & 7;
#pragma unroll
        for (int kk = 0; kk < 2; ++kk)
          af[kk][mi] = *(const bf16x8*)&At[(px << 6) + ((((kk << 2) | lq) ^ sw) << 3)];
      }
#pragma unroll
      for (int kk = 0; kk < 2; ++kk)
#pragma unroll
        for (int mi = 0; mi < 4; ++mi)
#pragma unroll
          for (int ni = 0; ni < 4; ++ni)
            acc[mi][ni] = __builtin_amdgcn_mfma_f32_16x16x32_bf16(af[kk][mi], bcur[kk][ni],
                                                                  acc[mi][ni], 0, 0, 0);
      if (o < 8) {
#pragma unroll
        for (int kk = 0; kk < 2; ++kk)
#pragma unroll
          for (int ni = 0; ni < 4; ++ni)
            bcur[kk][ni] = bnext[kk][ni];
      }
    }
    __syncthreads();   // protect At before next slice's staging
  }

  // epilogue: bias + relu (+store NHWC bf16 for aux) + fused mask 1x1 dot
  float bv[4], wv[4];
#pragma unroll
  for (int ni = 0; ni < 4; ++ni) {
    int cc = n_off + ni * 16 + ln;
    bv[ni] = bias[cc];
    wv[ni] = wmv[cc];
  }
  const int prow = (y0 + wrow) * 512 + x0;
#pragma unroll
  for (int mi = 0; mi < 4; ++mi) {
#pragma unroll
    for (int r = 0; r < 4; ++r) {
      int pix = prow + mi * 16 + (lq << 2) + r;   // D row = pixel col within tile
      float mp = 0.f;
#pragma unroll
      for (int ni = 0; ni < 4; ++ni) {
        float v = acc[mi][ni][r] + bv[ni];
        v = v > 0.f ? v : 0.f;
        if (aux) Out[((long)pix << 8) + (n_off + ni * 16 + ln)] = __float2bfloat16(v);
        mp += v * wv[ni];
      }
      mp += __shfl_xor(mp, 1);
      mp += __shfl_xor(mp, 2);
      mp += __shfl_xor(mp, 4);
      mp += __shfl_xor(mp, 8);
      if (ln == 0) atomicAdd(&maskacc[pix], mp);
    }
  }
}

// ---------------- mask sigmoid + final combine ---------------------------------
__global__ void mask_sigmoid(float* maskacc, const float* __restrict__ bm) {
  int i = blockIdx.x * 256 + threadIdx.x;
  float v = maskacc[i] + bm[0];
  maskacc[i] = 1.f / (1.f + expf(-v));
}

// out[c][p] = m[c][p] + mask[p] * M_aux_t[p][c]; aux transposed through LDS
__global__ void final_combine(const float* __restrict__ m,
                              const __hip_bfloat16* __restrict__ MauxT,
                              const float* __restrict__ mask,
                              float* __restrict__ out) {
  __shared__ __align__(16) __hip_bfloat16 tile[64 * 264];
  __shared__ float sm[64];
  int tid = threadIdx.x;
  int p0 = blockIdx.x * 64;
  if (tid < 64) sm[tid] = mask[p0 + tid];
#pragma unroll
  for (int j = 0; j < 8; ++j) {       // stage 64 px x 256 ch, coalesced uint4
    int f = j * 256 + tid;            // 0..2047
    int px = f >> 5, c8 = f & 31;
    *(uint4*)&tile[px * 264 + (c8 << 3)] =
        *(const uint4*)&MauxT[(((long)(p0 + px)) << 8) + (c8 << 3)];
  }
  __syncthreads();
  int px = tid & 63, w = tid >> 6;
  float mk = sm[px];
  for (int k = 0; k < 64; ++k) {
    int c = (k << 2) + w;
    long gi = (long)c * NPIX + p0 + px;
    out[gi] = m[gi] + mk * __bfloat162float(tile[px * 264 + c]);
  }
}

extern "C" void kernel_launch(void* const* d_in, const int* in_sizes, int n_in,
                              void* d_out, int out_size, void* d_ws, size_t ws_size,
                              hipStream_t stream) {
  const float* m  = (const float*)d_in[0];
  const float* fb = (const float*)d_in[1];  // face 0 (back)
  const float* fu = (const float*)d_in[2];  // face 5 (up)
  const float* fd = (const float*)d_in[3];  // face 1 (down)
  const float* Wf = (const float*)d_in[4];
  const float* bf = (const float*)d_in[5];
  const float* Wm = (const float*)d_in[6];
  const float* bm = (const float*)d_in[7];
  float* out = (float*)d_out;

  char* ws = (char*)d_ws;
  // Fast path layout (Ft aliases the Xp_m region; Ft is dead before nchw writes):
  //   [0, FT_BYTES)                 : Ft, then Xp_m (XP_STRIDE <= FT_BYTES)
  //   [FT_BYTES, +XP_STRIDE)        : Xp_aux
  //   then Wtt (1179648), MauxT (67108864), maskacc (524288)
  const size_t NEED_FAST = (size_t)FT_BYTES + XP_STRIDE + 1179648 + 67108864 + 524288; // 237,438,976

  if (ws_size >= NEED_FAST) {
    __hip_bfloat16* Ft     = (__hip_bfloat16*)(ws);
    __hip_bfloat16* Xp_m   = (__hip_bfloat16*)(ws);                       // aliases Ft (after Ft dead)
    __hip_bfloat16* Xp_aux = (__hip_bfloat16*)(ws + (size_t)FT_BYTES);
    __hip_bfloat16* Wtt    = (__hip_bfloat16*)(ws + (size_t)FT_BYTES + XP_STRIDE);
    __hip_bfloat16* MauxT  = (__hip_bfloat16*)(ws + (size_t)FT_BYTES + XP_STRIDE + 1179648);
    float* maskacc         = (float*)(ws + (size_t)FT_BYTES + XP_STRIDE + 1179648 + 67108864);

    face_to_nhwc<<<3072, 256, 0, stream>>>(fb, fd, fu, Ft);
    aux_gen_v2<<<32768, 256, 0, stream>>>(Ft, Xp_aux);      // Ft dead after this
    nchw_to_pad_nhwc<<<2048, 256, 0, stream>>>(m, Xp_m);    // overwrites Ft region
    zero_borders<<<dim3(1540, 2), 128, 0, stream>>>(Xp_m, Xp_aux);
    prep_weights<<<2304, 256, 0, stream>>>(Wf, Wtt);
    zero_mask<<<512, 256, 0, stream>>>(maskacc);
    conv3x3_mfma<<<dim3(1024, 2), 512, 0, stream>>>(Xp_aux, Xp_m, Wtt, bf, Wm, MauxT, maskacc);
    mask_sigmoid<<<512, 256, 0, stream>>>(maskacc, bm);
    final_combine<<<2048, 256, 0, stream>>>(m, MauxT, maskacc, out);
  } else {
    // Fallback: round-2 layout (~195.3 MiB), planar gather aux_gen
    __hip_bfloat16* Xp_m   = (__hip_bfloat16*)(ws);
    __hip_bfloat16* Xp_aux = (__hip_bfloat16*)(ws + (size_t)XP_STRIDE);
    __hip_bfloat16* Wtt    = (__hip_bfloat16*)(ws + 2uL * XP_STRIDE);
    __hip_bfloat16* MauxT  = (__hip_bfloat16*)(ws + 2uL * XP_STRIDE + 1179648);
    float* maskacc         = (float*)(ws + 2uL * XP_STRIDE + 1179648 + 67108864);

    zero_borders<<<dim3(1540, 2), 128, 0, stream>>>(Xp_m, Xp_aux);
    zero_mask<<<512, 256, 0, stream>>>(maskacc);
    prep_weights<<<2304, 256, 0, stream>>>(Wf, Wtt);
    nchw_to_pad_nhwc<<<2048, 256, 0, stream>>>(m, Xp_m);
    aux_gen<<<2048, 256, 0, stream>>>(fb, fd, fu, Xp_aux);
    conv3x3_mfma<<<dim3(1024, 2), 512, 0, stream>>>(Xp_aux, Xp_m, Wtt, bf, Wm, MauxT, maskacc);
    mask_sigmoid<<<512, 256, 0, stream>>>(maskacc, bm);
    final_combine<<<2048, 256, 0, stream>>>(m, MauxT, maskacc, out);
  }
}

// Round 5
// 772.854 us; speedup vs baseline: 6.1354x; 6.1354x over previous
//
#include <hip/hip_runtime.h>
#include <hip/hip_bf16.h>

// Problem constants: C=256 channels, equirect H=256 x W=512, faces 256x256.
// Padded NHWC conv-input layout: Xp[(H+2)=258 rows][(W+2)=514 cols][256 ch] bf16.
#define NPIX 131072        // 256*512
#define WP   514
#define XP_BYTES 67897344  // 258*514*256*2
#define XP_STRIDE 67962880 // XP_BYTES + 64KB slack (conv halo staging over-reads up to 7KB)
#define FT_BYTES 100663296 // 3 faces * 65536 px * 256 ch * 2B (NHWC bf16)

typedef __attribute__((ext_vector_type(8))) short bf16x8;  // 8 bf16 = 4 VGPRs
typedef __attribute__((ext_vector_type(4))) float f32x4;

typedef const __attribute__((address_space(1))) void g_cvoid;
typedef __attribute__((address_space(3))) void l_void;

__device__ __forceinline__ void async16(const void* g, void* l) {
  // width-16 global->LDS DMA; LDS dest = wave-uniform base + lane*16
  __builtin_amdgcn_global_load_lds((g_cvoid*)g, (l_void*)l, 16, 0, 0);
}

// ---------------- ws state init (ws is re-poisoned 0xAA before every launch) ---
__global__ void zero_borders(__hip_bfloat16* Xm, __hip_bfloat16* Xa) {
  int i = blockIdx.x;  // 0..1539 border pixels
  __hip_bfloat16* X = blockIdx.y ? Xa : Xm;
  long ppix;
  if (i < 514)       ppix = i;                                  // top row
  else if (i < 1028) ppix = 257L * WP + (i - 514);              // bottom row
  else if (i < 1284) ppix = (long)(i - 1028 + 1) * WP;          // left col
  else               ppix = (long)(i - 1284 + 1) * WP + 513;    // right col
  ((unsigned int*)(X + ppix * 256))[threadIdx.x] = 0u;          // 128 u32 = 256 bf16
}

__global__ void zero_mask(float* maskacc) {
  maskacc[blockIdx.x * 256 + threadIdx.x] = 0.f;
}

// Wf [cout][cin][3][3] fp32 -> Wtt [(o*32 + ci>>3)][cout][ci&7] bf16
// so a B fragment (quad lq, lane ln) reads 256B-contiguous, coalesced b128.
__global__ void prep_weights(const float* __restrict__ Wf, __hip_bfloat16* __restrict__ Wtt) {
  int idx = blockIdx.x * 256 + threadIdx.x;   // 589824 total
  int cout = idx / 2304, rem = idx % 2304;
  int o = rem >> 8, ci = rem & 255;
  Wtt[(((o << 5) + (ci >> 3)) << 11) + (cout << 3) + (ci & 7)] =
      __float2bfloat16(Wf[(cout * 256 + ci) * 9 + o]);
}

// ---------------- m (NCHW fp32) -> padded NHWC bf16 ----------------------------
__global__ void nchw_to_pad_nhwc(const float* __restrict__ src, __hip_bfloat16* __restrict__ Xp) {
  __shared__ __align__(16) __hip_bfloat16 tile[64 * 264];  // 64 px x 256 ch (+8 pad)
  int tid = threadIdx.x;
  int p0 = blockIdx.x * 64;
  int px = tid & 63, w = tid >> 6;
  for (int k = 0; k < 64; ++k) {
    int c = (k << 2) + w;
    tile[px * 264 + c] = __float2bfloat16(src[(long)c * NPIX + p0 + px]);
  }
  __syncthreads();
  int y = p0 >> 9, x0 = p0 & 511;
  long basep = (long)(y + 1) * WP + x0 + 1;
  for (int pass = 0; pass < 8; ++pass) {
    int tpx = (pass << 3) + (tid >> 5);
    int chunk = tid & 31;
    uint4 v = *(const uint4*)&tile[tpx * 264 + (chunk << 3)];
    *(uint4*)&Xp[(basep + tpx) * 256 + (chunk << 3)] = v;
  }
}

// ---------------- faces (NCHW fp32, 3 used faces) -> NHWC bf16 -----------------
__global__ void face_to_nhwc(const float* __restrict__ fb, const float* __restrict__ fd,
                             const float* __restrict__ fu, __hip_bfloat16* __restrict__ Ft) {
  __shared__ __align__(16) __hip_bfloat16 tile[64 * 264];
  int tid = threadIdx.x;
  int face = blockIdx.x >> 10;         // 0..2 (slot: 0=b,1=d,2=u)
  int p0 = (blockIdx.x & 1023) << 6;
  const float* src = (face == 0) ? fb : (face == 1) ? fd : fu;
  int px = tid & 63, w = tid >> 6;
  for (int k = 0; k < 64; ++k) {
    int c = (k << 2) + w;
    tile[px * 264 + c] = __float2bfloat16(src[(long)c * 65536 + p0 + px]);
  }
  __syncthreads();
  long basep = ((long)face << 16) + p0;
  for (int pass = 0; pass < 8; ++pass) {
    int tpx = (pass << 3) + (tid >> 5);
    int chunk = tid & 31;
    uint4 v = *(const uint4*)&tile[tpx * 264 + (chunk << 3)];
    *(uint4*)&Ft[((basep + tpx) << 8) + (chunk << 3)] = v;
  }
}

// ---------------- cube2equi sampling v2: one wave per output pixel -------------
// Ft is NHWC bf16: sample = 512B contiguous. Lane parity = u0/u1, lane>>1 = ch octet.
__device__ __forceinline__ void bf8_fma(uint4 q, float w, float* acc) {
  unsigned x;
  x = q.x; acc[0] += w * __uint_as_float(x << 16); acc[1] += w * __uint_as_float(x & 0xffff0000u);
  x = q.y; acc[2] += w * __uint_as_float(x << 16); acc[3] += w * __uint_as_float(x & 0xffff0000u);
  x = q.z; acc[4] += w * __uint_as_float(x << 16); acc[5] += w * __uint_as_float(x & 0xffff0000u);
  x = q.w; acc[6] += w * __uint_as_float(x << 16); acc[7] += w * __uint_as_float(x & 0xffff0000u);
}

__global__ void aux_gen_v2(const __hip_bfloat16* __restrict__ Ft,
                           __hip_bfloat16* __restrict__ Xp) {
  const int lane = threadIdx.x & 63;
  const int p = (blockIdx.x << 2) + (threadIdx.x >> 6);  // one wave per pixel
  const int yy = p >> 9, xx = p & 511;

  // geometry (wave-uniform; fast HW trig: v_sin/v_cos, ~2^-20 rel err vs 0.11 tol)
  float theta = ((xx + 0.5f) / 512.f) * 6.283185307179586f - 3.141592653589793f;
  float phi   = 1.5707963267948966f - ((yy + 0.5f) / 256.f) * 3.141592653589793f;
  float st = __sinf(theta), ct = __cosf(theta);
  float sp = __sinf(phi),   cp = __cosf(phi);
  float dx = cp * st, dy = sp, dz = cp * ct;
  float ax = fabsf(dx), ay = fabsf(dy), az = fabsf(dz);
  float mx = fmaxf(fmaxf(ax, ay), az);
  float pxn = dx / mx, pyn = dy / mx, pzn = dz / mx;
  bool cz = (az >= ax) && (az >= ay);
  bool cx = (!cz) && (ax >= ay);
  int face; float a, b;
  if (cz)      { face = dz > 0.f ? 2 : 0; a = dz > 0.f ? pxn : -pxn; b = -pyn; }
  else if (cx) { face = dx > 0.f ? 4 : 3; a = dx > 0.f ? -pzn : pzn; b = -pyn; }
  else         { face = dy > 0.f ? 5 : 1; a = pxn; b = dy > 0.f ? pzn : -pzn; }
  float uu = fminf(fmaxf((a + 1.f) * 0.5f * 255.f, 0.f), 255.f);
  float vv = fminf(fmaxf((b + 1.f) * 0.5f * 255.f, 0.f), 255.f);

  const long outbase = ((long)((yy + 1) * WP + xx + 1)) << 8;
  const int c0 = (lane >> 1) << 3;     // channel octet
  const int up = lane & 1;             // 0 -> u0, 1 -> u1
  const int slot = (face == 0) ? 0 : (face == 1) ? 1 : (face == 5) ? 2 : -1;

  if (slot < 0) {                      // faces 2/3/4 are the zero 'emptyFace'
    if (!up) *(uint4*)&Xp[outbase + c0] = make_uint4(0u, 0u, 0u, 0u);
    return;
  }
  int u0 = (int)uu, v0 = (int)vv;
  int u1 = min(u0 + 1, 255), v1 = min(v0 + 1, 255);
  float wu = uu - (float)u0, wv = vv - (float)v0;
  int uc = up ? u1 : u0;
  float wA = up ? wu : (1.f - wu);
  const __hip_bfloat16* base = Ft + ((long)slot << 24);  // slot * 65536 * 256

  float acc[8] = {0.f, 0.f, 0.f, 0.f, 0.f, 0.f, 0.f, 0.f};
  uint4 q0 = *(const uint4*)&base[(((long)(v0 << 8) + uc) << 8) + c0];
  uint4 q1 = *(const uint4*)&base[(((long)(v1 << 8) + uc) << 8) + c0];
  bf8_fma(q0, (1.f - wv) * wA, acc);
  bf8_fma(q1, wv * wA, acc);
#pragma unroll
  for (int j = 0; j < 8; ++j) acc[j] += __shfl_xor(acc[j], 1);
  if (!up) {
    union { uint4 q; __hip_bfloat16 h[8]; } o;
#pragma unroll
    for (int j = 0; j < 8; ++j) o.h[j] = __float2bfloat16(acc[j]);
    *(uint4*)&Xp[outbase + c0] = o.q;
  }
}

// ---------------- cube2equi v1 (fallback when ws too small for Ft) -------------
__global__ void aux_gen(const float* __restrict__ fb, const float* __restrict__ fd,
                        const float* __restrict__ fu,
                        __hip_bfloat16* __restrict__ Xp) {
  __shared__ __align__(16) __hip_bfloat16 tile[64 * 264];
  int tid = threadIdx.x;
  int p0 = blockIdx.x * 64;
  int px = tid & 63, w = tid >> 6;

  int p = p0 + px;
  int yy = p >> 9, xx = p & 511;
  float theta = ((xx + 0.5f) / 512.f) * 6.283185307179586f - 3.141592653589793f;
  float phi   = 1.5707963267948966f - ((yy + 0.5f) / 256.f) * 3.141592653589793f;
  float st = __sinf(theta), ct = __cosf(theta);
  float sp = __sinf(phi),   cp = __cosf(phi);
  float dx = cp * st, dy = sp, dz = cp * ct;
  float ax = fabsf(dx), ay = fabsf(dy), az = fabsf(dz);
  float mx = fmaxf(fmaxf(ax, ay), az);
  float pxn = dx / mx, pyn = dy / mx, pzn = dz / mx;
  bool cz = (az >= ax) && (az >= ay);
  bool cx = (!cz) && (ax >= ay);
  int face; float a, b;
  if (cz)      { face = dz > 0.f ? 2 : 0; a = dz > 0.f ? pxn : -pxn; b = -pyn; }
  else if (cx) { face = dx > 0.f ? 4 : 3; a = dx > 0.f ? -pzn : pzn; b = -pyn; }
  else         { face = dy > 0.f ? 5 : 1; a = pxn; b = dy > 0.f ? pzn : -pzn; }
  float uu = fminf(fmaxf((a + 1.f) * 0.5f * 255.f, 0.f), 255.f);
  float vv = fminf(fmaxf((b + 1.f) * 0.5f * 255.f, 0.f), 255.f);

  const float* F = (face == 0) ? fb : (face == 1) ? fd : (face == 5) ? fu : nullptr;
  int u0 = (int)uu, v0 = (int)vv;
  int u1 = min(u0 + 1, 255), v1 = min(v0 + 1, 255);
  float wu = uu - (float)u0, wv = vv - (float)v0;
  float w00 = (1.f - wv) * (1.f - wu), w01 = (1.f - wv) * wu;
  float w10 = wv * (1.f - wu),         w11 = wv * wu;
  int i00 = v0 * 256 + u0, i01 = v0 * 256 + u1;
  int i10 = v1 * 256 + u0, i11 = v1 * 256 + u1;
  for (int k = 0; k < 64; ++k) {
    int c = (k << 2) + w;
    float val = 0.f;
    if (F) {
      const float* Fc = F + ((long)c << 16);
      val = w00 * Fc[i00] + w01 * Fc[i01] + w10 * Fc[i10] + w11 * Fc[i11];
    }
    tile[px * 264 + c] = __float2bfloat16(val);
  }
  __syncthreads();
  int y = p0 >> 9, x0g = p0 & 511;
  long basep = (long)(y + 1) * WP + x0g + 1;
  for (int pass = 0; pass < 8; ++pass) {
    int tpx = (pass << 3) + (tid >> 5);
    int chunk = tid & 31;
    uint4 v = *(const uint4*)&tile[tpx * 264 + (chunk << 3)];
    *(uint4*)&Xp[(basep + tpx) * 256 + (chunk << 3)] = v;
  }
}

// ---------------- 3x3 conv as implicit GEMM (MFMA bf16) ------------------------
// v6: the verified pieces of v5 without its register blunders.
//  - BK=64 (4 ci-slices, 8 barriers) and the both-sides XOR swizzle are KEPT:
//    both were hardware-verified in round 3 (passed; SQ_LDS_BANK_CONFLICT = 0).
//  - REVERTED: __launch_bounds__(512,8) capped the unified file at 64 regs/lane
//    (8 waves/EU -> 512/8), which cannot hold the 64-reg accumulator -> scratch
//    spill (VGPR=32, 17 GB HBM traffic, 4.4 ms). Back to (512,4): 128-reg cap,
//    round 2's proven 64 VGPR + 64 AGPR no-spill configuration.
//  - REVERTED: B-tap-ahead double-buffer (+64 VGPRs). Wtt is L2-resident;
//    per-tap loads are covered by TLP at 16 waves/CU.
// grid = dim3(1024, 2): y==0 -> aux conv (stores MauxT), y==1 -> main conv.
// XCD strip swizzle: 1024 % 8 == 0 -> bijective.
__global__ __launch_bounds__(512, 4)
void conv3x3_mfma(const __hip_bfloat16* __restrict__ Xpa,
                  const __hip_bfloat16* __restrict__ Xpm,
                  const __hip_bfloat16* __restrict__ Wtt,
                  const float* __restrict__ bias,
                  const float* __restrict__ wm,
                  __hip_bfloat16* __restrict__ Out,
                  float* __restrict__ maskacc) {
  __shared__ __align__(16) __hip_bfloat16 At[4 * 80 * 64];   // 40960 B halo (4 rows x 80 px x 64 ch)
  const int tid = threadIdx.x;
  const int wave = tid >> 6, lane = tid & 63;
  const bool aux = (blockIdx.y == 0);
  const __hip_bfloat16* __restrict__ Xp = aux ? Xpa : Xpm;
  const float* __restrict__ wmv = aux ? wm + 256 : wm;

  const int tile = ((blockIdx.x & 7) << 7) + (blockIdx.x >> 3);  // strip -> XCD
  const int x0 = (tile >> 7) << 6;     // col strip (8 strips of 64)
  const int y0 = (tile & 127) << 1;    // row pair (rows vary fastest per XCD)
  const int wrow = wave >> 2;          // this wave's pixel row within tile (0/1)
  const int n_off = (wave & 3) << 6;   // this wave's cout quarter (0/64/128/192)
  const int lq = lane >> 4, ln = lane & 15;

  // halo staging: wave pair (srow = wave>>1) stages padded row (y0 + srow);
  // even wave covers 8-px chunks {0,8,16,24,32}, odd {40,48,56,64,72}.
  // One async16 = 8 px x 8 ci-octets (1024B). Lane l -> px offset l>>3, LDS
  // slot l&7; it fetches GLOBAL octet (l&7)^(l>>3), so LDS slot s of pixel p
  // holds logical octet s^(p&7)  (chunk bases and srow*80 are 0 mod 8).
  const int srow = wave >> 1;
  const long stage_row = (long)(y0 + srow) * WP + x0;
  const int q_px = lane >> 3;                     // 0..7 pixel offset in chunk
  const int q_ci = ((lane & 7) ^ q_px) << 3;      // swizzled ci offset 0..56

  f32x4 acc[4][4] = {};   // [mi (16-px col group)][ni (16-cout group)]

  for (int s = 0; s < 4; ++s) {
    const int ci0 = s << 6;
#pragma unroll
    for (int j = 0; j < 5; ++j) {
      const int chunk = ((wave & 1) ? 40 : 0) + (j << 3);
      async16(Xp + ((stage_row + chunk + q_px) << 8) + ci0 + q_ci,
              &At[(srow * 80 + chunk) << 6]);
    }
    __syncthreads();   // drains vmcnt -> staged halo visible to all waves
#pragma unroll
    for (int o = 0; o < 9; ++o) {
      const int dy = o / 3, dxo = o % 3;
      const int arow = (wrow + dy) * 80;
#pragma unroll
      for (int kk = 0; kk < 2; ++kk) {
        bf16x8 af[4], bb[4];
#pragma unroll
        for (int mi = 0; mi < 4; ++mi) {
          const int px = arow + mi * 16 + ln + dxo;   // arow = 0 mod 8
          af[mi] = *(const bf16x8*)&At[(px << 6) + ((((kk << 2) | lq) ^ (px & 7)) << 3)];
        }
#pragma unroll
        for (int ni = 0; ni < 4; ++ni)
          bb[ni] = *(const bf16x8*)&Wtt[(((o << 5) + (s << 3) + (kk << 2) + lq) << 11) +
                                        ((n_off + ni * 16 + ln) << 3)];
#pragma unroll
        for (int mi = 0; mi < 4; ++mi)
#pragma unroll
          for (int ni = 0; ni < 4; ++ni)
            acc[mi][ni] = __builtin_amdgcn_mfma_f32_16x16x32_bf16(af[mi], bb[ni],
                                                                  acc[mi][ni], 0, 0, 0);
      }
    }
    __syncthreads();   // protect At before next slice's staging
  }

  // epilogue: bias + relu (+store NHWC bf16 for aux) + fused mask 1x1 dot
  float bv[4], wv[4];
#pragma unroll
  for (int ni = 0; ni < 4; ++ni) {
    int cc = n_off + ni * 16 + ln;
    bv[ni] = bias[cc];
    wv[ni] = wmv[cc];
  }
  const int prow = (y0 + wrow) * 512 + x0;
#pragma unroll
  for (int mi = 0; mi < 4; ++mi) {
#pragma unroll
    for (int r = 0; r < 4; ++r) {
      int pix = prow + mi * 16 + (lq << 2) + r;   // D row = pixel col within tile
      float mp = 0.f;
#pragma unroll
      for (int ni = 0; ni < 4; ++ni) {
        float v = acc[mi][ni][r] + bv[ni];
        v = v > 0.f ? v : 0.f;
        if (aux) Out[((long)pix << 8) + (n_off + ni * 16 + ln)] = __float2bfloat16(v);
        mp += v * wv[ni];
      }
      mp += __shfl_xor(mp, 1);
      mp += __shfl_xor(mp, 2);
      mp += __shfl_xor(mp, 4);
      mp += __shfl_xor(mp, 8);
      if (ln == 0) atomicAdd(&maskacc[pix], mp);
    }
  }
}

// ---------------- mask sigmoid + final combine ---------------------------------
__global__ void mask_sigmoid(float* maskacc, const float* __restrict__ bm) {
  int i = blockIdx.x * 256 + threadIdx.x;
  float v = maskacc[i] + bm[0];
  maskacc[i] = 1.f / (1.f + expf(-v));
}

// out[c][p] = m[c][p] + mask[p] * M_aux_t[p][c]; aux transposed through LDS
__global__ void final_combine(const float* __restrict__ m,
                              const __hip_bfloat16* __restrict__ MauxT,
                              const float* __restrict__ mask,
                              float* __restrict__ out) {
  __shared__ __align__(16) __hip_bfloat16 tile[64 * 264];
  __shared__ float sm[64];
  int tid = threadIdx.x;
  int p0 = blockIdx.x * 64;
  if (tid < 64) sm[tid] = mask[p0 + tid];
#pragma unroll
  for (int j = 0; j < 8; ++j) {       // stage 64 px x 256 ch, coalesced uint4
    int f = j * 256 + tid;            // 0..2047
    int px = f >> 5, c8 = f & 31;
    *(uint4*)&tile[px * 264 + (c8 << 3)] =
        *(const uint4*)&MauxT[(((long)(p0 + px)) << 8) + (c8 << 3)];
  }
  __syncthreads();
  int px = tid & 63, w = tid >> 6;
  float mk = sm[px];
  for (int k = 0; k < 64; ++k) {
    int c = (k << 2) + w;
    long gi = (long)c * NPIX + p0 + px;
    out[gi] = m[gi] + mk * __bfloat162float(tile[px * 264 + c]);
  }
}

extern "C" void kernel_launch(void* const* d_in, const int* in_sizes, int n_in,
                              void* d_out, int out_size, void* d_ws, size_t ws_size,
                              hipStream_t stream) {
  const float* m  = (const float*)d_in[0];
  const float* fb = (const float*)d_in[1];  // face 0 (back)
  const float* fu = (const float*)d_in[2];  // face 5 (up)
  const float* fd = (const float*)d_in[3];  // face 1 (down)
  const float* Wf = (const float*)d_in[4];
  const float* bf = (const float*)d_in[5];
  const float* Wm = (const float*)d_in[6];
  const float* bm = (const float*)d_in[7];
  float* out = (float*)d_out;

  char* ws = (char*)d_ws;
  // Fast path layout (Ft aliases the Xp_m region; Ft is dead before nchw writes):
  //   [0, FT_BYTES)                 : Ft, then Xp_m (XP_STRIDE <= FT_BYTES)
  //   [FT_BYTES, +XP_STRIDE)        : Xp_aux
  //   then Wtt (1179648), MauxT (67108864), maskacc (524288)
  const size_t NEED_FAST = (size_t)FT_BYTES + XP_STRIDE + 1179648 + 67108864 + 524288; // 237,438,976

  if (ws_size >= NEED_FAST) {
    __hip_bfloat16* Ft     = (__hip_bfloat16*)(ws);
    __hip_bfloat16* Xp_m   = (__hip_bfloat16*)(ws);                       // aliases Ft (after Ft dead)
    __hip_bfloat16* Xp_aux = (__hip_bfloat16*)(ws + (size_t)FT_BYTES);
    __hip_bfloat16* Wtt    = (__hip_bfloat16*)(ws + (size_t)FT_BYTES + XP_STRIDE);
    __hip_bfloat16* MauxT  = (__hip_bfloat16*)(ws + (size_t)FT_BYTES + XP_STRIDE + 1179648);
    float* maskacc         = (float*)(ws + (size_t)FT_BYTES + XP_STRIDE + 1179648 + 67108864);

    face_to_nhwc<<<3072, 256, 0, stream>>>(fb, fd, fu, Ft);
    aux_gen_v2<<<32768, 256, 0, stream>>>(Ft, Xp_aux);      // Ft dead after this
    nchw_to_pad_nhwc<<<2048, 256, 0, stream>>>(m, Xp_m);    // overwrites Ft region
    zero_borders<<<dim3(1540, 2), 128, 0, stream>>>(Xp_m, Xp_aux);
    prep_weights<<<2304, 256, 0, stream>>>(Wf, Wtt);
    zero_mask<<<512, 256, 0, stream>>>(maskacc);
    conv3x3_mfma<<<dim3(1024, 2), 512, 0, stream>>>(Xp_aux, Xp_m, Wtt, bf, Wm, MauxT, maskacc);
    mask_sigmoid<<<512, 256, 0, stream>>>(maskacc, bm);
    final_combine<<<2048, 256, 0, stream>>>(m, MauxT, maskacc, out);
  } else {
    // Fallback: round-2 layout (~195.3 MiB), planar gather aux_gen
    __hip_bfloat16* Xp_m   = (__hip_bfloat16*)(ws);
    __hip_bfloat16* Xp_aux = (__hip_bfloat16*)(ws + (size_t)XP_STRIDE);
    __hip_bfloat16* Wtt    = (__hip_bfloat16*)(ws + 2uL * XP_STRIDE);
    __hip_bfloat16* MauxT  = (__hip_bfloat16*)(ws + 2uL * XP_STRIDE + 1179648);
    float* maskacc         = (float*)(ws + 2uL * XP_STRIDE + 1179648 + 67108864);

    zero_borders<<<dim3(1540, 2), 128, 0, stream>>>(Xp_m, Xp_aux);
    zero_mask<<<512, 256, 0, stream>>>(maskacc);
    prep_weights<<<2304, 256, 0, stream>>>(Wf, Wtt);
    nchw_to_pad_nhwc<<<2048, 256, 0, stream>>>(m, Xp_m);
    aux_gen<<<2048, 256, 0, stream>>>(fb, fd, fu, Xp_aux);
    conv3x3_mfma<<<dim3(1024, 2), 512, 0, stream>>>(Xp_aux, Xp_m, Wtt, bf, Wm, MauxT, maskacc);
    mask_sigmoid<<<512, 256, 0, stream>>>(maskacc, bm);
    final_combine<<<2048, 256, 0, stream>>>(m, MauxT, maskacc, out);
  }
}

// Round 6
// 741.447 us; speedup vs baseline: 6.3953x; 1.0424x over previous
//
#include <hip/hip_runtime.h>
#include <hip/hip_bf16.h>

// Problem constants: C=256 channels, equirect H=256 x W=512, faces 256x256.
// Padded NHWC conv-input layout: Xp[(H+2)=258 rows][(W+2)=514 cols][256 ch] bf16.
#define NPIX 131072        // 256*512
#define WP   514
#define XP_BYTES 67897344  // 258*514*256*2
#define XP_STRIDE 67962880 // XP_BYTES + 64KB slack (conv halo staging over-reads up to 7KB)
#define FT_BYTES 100663296 // 3 faces * 65536 px * 256 ch * 2B (NHWC bf16)

typedef __attribute__((ext_vector_type(8))) short bf16x8;  // 8 bf16 = 4 VGPRs
typedef __attribute__((ext_vector_type(4))) float f32x4;

typedef const __attribute__((address_space(1))) void g_cvoid;
typedef __attribute__((address_space(3))) void l_void;

__device__ __forceinline__ void async16(const void* g, void* l) {
  // width-16 global->LDS DMA; LDS dest = wave-uniform base + lane*16
  __builtin_amdgcn_global_load_lds((g_cvoid*)g, (l_void*)l, 16, 0, 0);
}

// ---------------- ws state init (ws is re-poisoned 0xAA before every launch) ---
__global__ void zero_borders(__hip_bfloat16* Xm, __hip_bfloat16* Xa) {
  int i = blockIdx.x;  // 0..1539 border pixels
  __hip_bfloat16* X = blockIdx.y ? Xa : Xm;
  long ppix;
  if (i < 514)       ppix = i;                                  // top row
  else if (i < 1028) ppix = 257L * WP + (i - 514);              // bottom row
  else if (i < 1284) ppix = (long)(i - 1028 + 1) * WP;          // left col
  else               ppix = (long)(i - 1284 + 1) * WP + 513;    // right col
  ((unsigned int*)(X + ppix * 256))[threadIdx.x] = 0u;          // 128 u32 = 256 bf16
}

__global__ void zero_mask(float* maskacc) {
  maskacc[blockIdx.x * 256 + threadIdx.x] = 0.f;
}

// Wf [cout][cin][3][3] fp32 -> Wtt [(o*32 + ci>>3)][cout][ci&7] bf16
// so a B fragment (quad lq, lane ln) reads 256B-contiguous, coalesced b128.
__global__ void prep_weights(const float* __restrict__ Wf, __hip_bfloat16* __restrict__ Wtt) {
  int idx = blockIdx.x * 256 + threadIdx.x;   // 589824 total
  int cout = idx / 2304, rem = idx % 2304;
  int o = rem >> 8, ci = rem & 255;
  Wtt[(((o << 5) + (ci >> 3)) << 11) + (cout << 3) + (ci & 7)] =
      __float2bfloat16(Wf[(cout * 256 + ci) * 9 + o]);
}

// ---------------- m (NCHW fp32) -> padded NHWC bf16 ----------------------------
// G13: planar reads vectorized to float4 (4 px/lane, 16 iters) -- hipcc never
// auto-vectorizes scalar fp32 loads; this quarters the VMEM issue count.
__global__ void nchw_to_pad_nhwc(const float* __restrict__ src, __hip_bfloat16* __restrict__ Xp) {
  __shared__ __align__(16) __hip_bfloat16 tile[64 * 264];  // 64 px x 256 ch (+8 pad)
  int tid = threadIdx.x;
  int p0 = blockIdx.x * 64;
  int cw = tid >> 4;            // 0..15 channel subgroup
  int px4 = (tid & 15) << 2;    // 0,4,...,60
  for (int it = 0; it < 16; ++it) {
    int c = (it << 4) + cw;
    float4 v = *(const float4*)&src[(long)c * NPIX + p0 + px4];
    tile[(px4 + 0) * 264 + c] = __float2bfloat16(v.x);
    tile[(px4 + 1) * 264 + c] = __float2bfloat16(v.y);
    tile[(px4 + 2) * 264 + c] = __float2bfloat16(v.z);
    tile[(px4 + 3) * 264 + c] = __float2bfloat16(v.w);
  }
  __syncthreads();
  int y = p0 >> 9, x0 = p0 & 511;
  long basep = (long)(y + 1) * WP + x0 + 1;
  for (int pass = 0; pass < 8; ++pass) {
    int tpx = (pass << 3) + (tid >> 5);
    int chunk = tid & 31;
    uint4 v = *(const uint4*)&tile[tpx * 264 + (chunk << 3)];
    *(uint4*)&Xp[(basep + tpx) * 256 + (chunk << 3)] = v;
  }
}

// ---------------- faces (NCHW fp32, 3 used faces) -> NHWC bf16 -----------------
__global__ void face_to_nhwc(const float* __restrict__ fb, const float* __restrict__ fd,
                             const float* __restrict__ fu, __hip_bfloat16* __restrict__ Ft) {
  __shared__ __align__(16) __hip_bfloat16 tile[64 * 264];
  int tid = threadIdx.x;
  int face = blockIdx.x >> 10;         // 0..2 (slot: 0=b,1=d,2=u)
  int p0 = (blockIdx.x & 1023) << 6;
  const float* src = (face == 0) ? fb : (face == 1) ? fd : fu;
  int cw = tid >> 4;            // 0..15
  int px4 = (tid & 15) << 2;    // 0,4,...,60
  for (int it = 0; it < 16; ++it) {
    int c = (it << 4) + cw;
    float4 v = *(const float4*)&src[(long)c * 65536 + p0 + px4];
    tile[(px4 + 0) * 264 + c] = __float2bfloat16(v.x);
    tile[(px4 + 1) * 264 + c] = __float2bfloat16(v.y);
    tile[(px4 + 2) * 264 + c] = __float2bfloat16(v.z);
    tile[(px4 + 3) * 264 + c] = __float2bfloat16(v.w);
  }
  __syncthreads();
  long basep = ((long)face << 16) + p0;
  for (int pass = 0; pass < 8; ++pass) {
    int tpx = (pass << 3) + (tid >> 5);
    int chunk = tid & 31;
    uint4 v = *(const uint4*)&tile[tpx * 264 + (chunk << 3)];
    *(uint4*)&Ft[((basep + tpx) << 8) + (chunk << 3)] = v;
  }
}

// ---------------- cube2equi sampling v2: one wave per output pixel -------------
// Ft is NHWC bf16: sample = 512B contiguous. Lane parity = u0/u1, lane>>1 = ch octet.
__device__ __forceinline__ void bf8_fma(uint4 q, float w, float* acc) {
  unsigned x;
  x = q.x; acc[0] += w * __uint_as_float(x << 16); acc[1] += w * __uint_as_float(x & 0xffff0000u);
  x = q.y; acc[2] += w * __uint_as_float(x << 16); acc[3] += w * __uint_as_float(x & 0xffff0000u);
  x = q.z; acc[4] += w * __uint_as_float(x << 16); acc[5] += w * __uint_as_float(x & 0xffff0000u);
  x = q.w; acc[6] += w * __uint_as_float(x << 16); acc[7] += w * __uint_as_float(x & 0xffff0000u);
}

__global__ void aux_gen_v2(const __hip_bfloat16* __restrict__ Ft,
                           __hip_bfloat16* __restrict__ Xp) {
  const int lane = threadIdx.x & 63;
  const int p = (blockIdx.x << 2) + (threadIdx.x >> 6);  // one wave per pixel
  const int yy = p >> 9, xx = p & 511;

  // geometry (wave-uniform; fast HW trig: v_sin/v_cos, ~2^-20 rel err vs 0.11 tol)
  float theta = ((xx + 0.5f) / 512.f) * 6.283185307179586f - 3.141592653589793f;
  float phi   = 1.5707963267948966f - ((yy + 0.5f) / 256.f) * 3.141592653589793f;
  float st = __sinf(theta), ct = __cosf(theta);
  float sp = __sinf(phi),   cp = __cosf(phi);
  float dx = cp * st, dy = sp, dz = cp * ct;
  float ax = fabsf(dx), ay = fabsf(dy), az = fabsf(dz);
  float mx = fmaxf(fmaxf(ax, ay), az);
  float pxn = dx / mx, pyn = dy / mx, pzn = dz / mx;
  bool cz = (az >= ax) && (az >= ay);
  bool cx = (!cz) && (ax >= ay);
  int face; float a, b;
  if (cz)      { face = dz > 0.f ? 2 : 0; a = dz > 0.f ? pxn : -pxn; b = -pyn; }
  else if (cx) { face = dx > 0.f ? 4 : 3; a = dx > 0.f ? -pzn : pzn; b = -pyn; }
  else         { face = dy > 0.f ? 5 : 1; a = pxn; b = dy > 0.f ? pzn : -pzn; }
  float uu = fminf(fmaxf((a + 1.f) * 0.5f * 255.f, 0.f), 255.f);
  float vv = fminf(fmaxf((b + 1.f) * 0.5f * 255.f, 0.f), 255.f);

  const long outbase = ((long)((yy + 1) * WP + xx + 1)) << 8;
  const int c0 = (lane >> 1) << 3;     // channel octet
  const int up = lane & 1;             // 0 -> u0, 1 -> u1
  const int slot = (face == 0) ? 0 : (face == 1) ? 1 : (face == 5) ? 2 : -1;

  if (slot < 0) {                      // faces 2/3/4 are the zero 'emptyFace'
    if (!up) *(uint4*)&Xp[outbase + c0] = make_uint4(0u, 0u, 0u, 0u);
    return;
  }
  int u0 = (int)uu, v0 = (int)vv;
  int u1 = min(u0 + 1, 255), v1 = min(v0 + 1, 255);
  float wu = uu - (float)u0, wv = vv - (float)v0;
  int uc = up ? u1 : u0;
  float wA = up ? wu : (1.f - wu);
  const __hip_bfloat16* base = Ft + ((long)slot << 24);  // slot * 65536 * 256

  float acc[8] = {0.f, 0.f, 0.f, 0.f, 0.f, 0.f, 0.f, 0.f};
  uint4 q0 = *(const uint4*)&base[(((long)(v0 << 8) + uc) << 8) + c0];
  uint4 q1 = *(const uint4*)&base[(((long)(v1 << 8) + uc) << 8) + c0];
  bf8_fma(q0, (1.f - wv) * wA, acc);
  bf8_fma(q1, wv * wA, acc);
#pragma unroll
  for (int j = 0; j < 8; ++j) acc[j] += __shfl_xor(acc[j], 1);
  if (!up) {
    union { uint4 q; __hip_bfloat16 h[8]; } o;
#pragma unroll
    for (int j = 0; j < 8; ++j) o.h[j] = __float2bfloat16(acc[j]);
    *(uint4*)&Xp[outbase + c0] = o.q;
  }
}

// ---------------- cube2equi v1 (fallback when ws too small for Ft) -------------
__global__ void aux_gen(const float* __restrict__ fb, const float* __restrict__ fd,
                        const float* __restrict__ fu,
                        __hip_bfloat16* __restrict__ Xp) {
  __shared__ __align__(16) __hip_bfloat16 tile[64 * 264];
  int tid = threadIdx.x;
  int p0 = blockIdx.x * 64;
  int px = tid & 63, w = tid >> 6;

  int p = p0 + px;
  int yy = p >> 9, xx = p & 511;
  float theta = ((xx + 0.5f) / 512.f) * 6.283185307179586f - 3.141592653589793f;
  float phi   = 1.5707963267948966f - ((yy + 0.5f) / 256.f) * 3.141592653589793f;
  float st = __sinf(theta), ct = __cosf(theta);
  float sp = __sinf(phi),   cp = __cosf(phi);
  float dx = cp * st, dy = sp, dz = cp * ct;
  float ax = fabsf(dx), ay = fabsf(dy), az = fabsf(dz);
  float mx = fmaxf(fmaxf(ax, ay), az);
  float pxn = dx / mx, pyn = dy / mx, pzn = dz / mx;
  bool cz = (az >= ax) && (az >= ay);
  bool cx = (!cz) && (ax >= ay);
  int face; float a, b;
  if (cz)      { face = dz > 0.f ? 2 : 0; a = dz > 0.f ? pxn : -pxn; b = -pyn; }
  else if (cx) { face = dx > 0.f ? 4 : 3; a = dx > 0.f ? -pzn : pzn; b = -pyn; }
  else         { face = dy > 0.f ? 5 : 1; a = pxn; b = dy > 0.f ? pzn : -pzn; }
  float uu = fminf(fmaxf((a + 1.f) * 0.5f * 255.f, 0.f), 255.f);
  float vv = fminf(fmaxf((b + 1.f) * 0.5f * 255.f, 0.f), 255.f);

  const float* F = (face == 0) ? fb : (face == 1) ? fd : (face == 5) ? fu : nullptr;
  int u0 = (int)uu, v0 = (int)vv;
  int u1 = min(u0 + 1, 255), v1 = min(v0 + 1, 255);
  float wu = uu - (float)u0, wv = vv - (float)v0;
  float w00 = (1.f - wv) * (1.f - wu), w01 = (1.f - wv) * wu;
  float w10 = wv * (1.f - wu),         w11 = wv * wu;
  int i00 = v0 * 256 + u0, i01 = v0 * 256 + u1;
  int i10 = v1 * 256 + u0, i11 = v1 * 256 + u1;
  for (int k = 0; k < 64; ++k) {
    int c = (k << 2) + w;
    float val = 0.f;
    if (F) {
      const float* Fc = F + ((long)c << 16);
      val = w00 * Fc[i00] + w01 * Fc[i01] + w10 * Fc[i10] + w11 * Fc[i11];
    }
    tile[px * 264 + c] = __float2bfloat16(val);
  }
  __syncthreads();
  int y = p0 >> 9, x0g = p0 & 511;
  long basep = (long)(y + 1) * WP + x0g + 1;
  for (int pass = 0; pass < 8; ++pass) {
    int tpx = (pass << 3) + (tid >> 5);
    int chunk = tid & 31;
    uint4 v = *(const uint4*)&tile[tpx * 264 + (chunk << 3)];
    *(uint4*)&Xp[(basep + tpx) * 256 + (chunk << 3)] = v;
  }
}

// ---------------- 3x3 conv as implicit GEMM (MFMA bf16) ------------------------
// v7 == round-2 v4 EXACTLY (proven 288us, MfmaUtil 48, no spill).
// Register post-mortem (round 5): this kernel sits exactly at the 64-arch-VGPR
// cap of __launch_bounds__(512,4) (64 VGPR + 64 AGPR acc). ANY addition to the
// inner loop spills silently to scratch (v6: +~16 dwords/thread -> +184MB HBM
// traffic, 353us). Do not add swizzle/BK changes here without first buying
// register headroom. BK=32, two-barrier-per-slice, 20KB single LDS buffer.
// grid = dim3(1024, 2): y==0 -> aux conv (stores MauxT), y==1 -> main conv.
// XCD strip swizzle: 1024 % 8 == 0 -> bijective.
__global__ __launch_bounds__(512, 4)
void conv3x3_mfma(const __hip_bfloat16* __restrict__ Xpa,
                  const __hip_bfloat16* __restrict__ Xpm,
                  const __hip_bfloat16* __restrict__ Wtt,
                  const float* __restrict__ bias,
                  const float* __restrict__ wm,
                  __hip_bfloat16* __restrict__ Out,
                  float* __restrict__ maskacc) {
  __shared__ __align__(16) __hip_bfloat16 At[4 * 80 * 32];   // 20480 B halo
  const int tid = threadIdx.x;
  const int wave = tid >> 6, lane = tid & 63;
  const bool aux = (blockIdx.y == 0);
  const __hip_bfloat16* __restrict__ Xp = aux ? Xpa : Xpm;
  const float* __restrict__ wmv = aux ? wm + 256 : wm;

  const int tile = ((blockIdx.x & 7) << 7) + (blockIdx.x >> 3);  // strip -> XCD
  const int x0 = (tile >> 7) << 6;     // col strip (8 strips of 64)
  const int y0 = (tile & 127) << 1;    // row pair (rows vary fastest per XCD)
  const int wrow = wave >> 2;          // this wave's pixel row within tile (0/1)
  const int n_off = (wave & 3) << 6;   // this wave's cout quarter (0/64/128/192)
  const int lq = lane >> 4, ln = lane & 15;

  // halo staging: wave pair (srow = wave>>1) stages padded row (y0 + srow);
  // even wave covers col chunks {0,16,32}, odd wave {48,64} (80 cols total)
  const int srow = wave >> 1;
  const long stage_row = (long)(y0 + srow) * WP + x0;
  const int s_col = lane >> 2;           // 0..15
  const int s_ci  = (lane & 3) << 3;     // 0,8,16,24

  f32x4 acc[4][4] = {};   // [mi (16-px col group)][ni (16-cout group)]

  for (int s = 0; s < 8; ++s) {
    const int ci0 = s << 5;
    if (wave & 1) {
      async16(Xp + ((stage_row + 48 + s_col) << 8) + ci0 + s_ci, &At[(srow * 80 + 48) << 5]);
      async16(Xp + ((stage_row + 64 + s_col) << 8) + ci0 + s_ci, &At[(srow * 80 + 64) << 5]);
    } else {
      async16(Xp + ((stage_row +  0 + s_col) << 8) + ci0 + s_ci, &At[(srow * 80 +  0) << 5]);
      async16(Xp + ((stage_row + 16 + s_col) << 8) + ci0 + s_ci, &At[(srow * 80 + 16) << 5]);
      async16(Xp + ((stage_row + 32 + s_col) << 8) + ci0 + s_ci, &At[(srow * 80 + 32) << 5]);
    }
    __syncthreads();   // drains vmcnt -> staged halo visible to all waves
#pragma unroll
    for (int o = 0; o < 9; ++o) {
      const int dy = o / 3, dxo = o % 3;
      const int arow = (wrow + dy) * 80;
      bf16x8 af[4], bb[4];
#pragma unroll
      for (int mi = 0; mi < 4; ++mi)
        af[mi] = *(const bf16x8*)&At[((arow + mi * 16 + ln + dxo) << 5) + (lq << 3)];
#pragma unroll
      for (int ni = 0; ni < 4; ++ni)
        bb[ni] = *(const bf16x8*)&Wtt[(((o << 5) + (s << 2) + lq) << 11) +
                                      ((n_off + ni * 16 + ln) << 3)];
#pragma unroll
      for (int mi = 0; mi < 4; ++mi)
#pragma unroll
        for (int ni = 0; ni < 4; ++ni)
          acc[mi][ni] = __builtin_amdgcn_mfma_f32_16x16x32_bf16(af[mi], bb[ni], acc[mi][ni], 0, 0, 0);
    }
    __syncthreads();   // protect At before next slice's staging
  }

  // epilogue: bias + relu (+store NHWC bf16 for aux) + fused mask 1x1 dot
  float bv[4], wv[4];
#pragma unroll
  for (int ni = 0; ni < 4; ++ni) {
    int cc = n_off + ni * 16 + ln;
    bv[ni] = bias[cc];
    wv[ni] = wmv[cc];
  }
  const int prow = (y0 + wrow) * 512 + x0;
#pragma unroll
  for (int mi = 0; mi < 4; ++mi) {
#pragma unroll
    for (int r = 0; r < 4; ++r) {
      int pix = prow + mi * 16 + (lq << 2) + r;   // D row = pixel col within tile
      float mp = 0.f;
#pragma unroll
      for (int ni = 0; ni < 4; ++ni) {
        float v = acc[mi][ni][r] + bv[ni];
        v = v > 0.f ? v : 0.f;
        if (aux) Out[((long)pix << 8) + (n_off + ni * 16 + ln)] = __float2bfloat16(v);
        mp += v * wv[ni];
      }
      mp += __shfl_xor(mp, 1);
      mp += __shfl_xor(mp, 2);
      mp += __shfl_xor(mp, 4);
      mp += __shfl_xor(mp, 8);
      if (ln == 0) atomicAdd(&maskacc[pix], mp);
    }
  }
}

// ---------------- final combine (sigmoid fused) --------------------------------
// out[c][p] = m[c][p] + sigmoid(maskacc[p]+bm)*M_aux_t[p][c]; aux via LDS.
// G13: m-read/out-write vectorized to float4 (4 px/lane, 16 iters).
__global__ void final_combine(const float* __restrict__ m,
                              const __hip_bfloat16* __restrict__ MauxT,
                              const float* __restrict__ maskacc,
                              const float* __restrict__ bm,
                              float* __restrict__ out) {
  __shared__ __align__(16) __hip_bfloat16 tile[64 * 264];
  __shared__ float sm[64];
  int tid = threadIdx.x;
  int p0 = blockIdx.x * 64;
  if (tid < 64) {
    float v = maskacc[p0 + tid] + bm[0];
    sm[tid] = 1.f / (1.f + expf(-v));
  }
#pragma unroll
  for (int j = 0; j < 8; ++j) {       // stage 64 px x 256 ch, coalesced uint4
    int f = j * 256 + tid;            // 0..2047
    int px = f >> 5, c8 = f & 31;
    *(uint4*)&tile[px * 264 + (c8 << 3)] =
        *(const uint4*)&MauxT[(((long)(p0 + px)) << 8) + (c8 << 3)];
  }
  __syncthreads();
  int cw = tid >> 4;            // 0..15 channel subgroup
  int px4 = (tid & 15) << 2;    // 0,4,...,60
  for (int it = 0; it < 16; ++it) {
    int c = (it << 4) + cw;
    long gi = (long)c * NPIX + p0 + px4;
    float4 mv = *(const float4*)&m[gi];
    float4 o;
    o.x = mv.x + sm[px4 + 0] * __bfloat162float(tile[(px4 + 0) * 264 + c]);
    o.y = mv.y + sm[px4 + 1] * __bfloat162float(tile[(px4 + 1) * 264 + c]);
    o.z = mv.z + sm[px4 + 2] * __bfloat162float(tile[(px4 + 2) * 264 + c]);
    o.w = mv.w + sm[px4 + 3] * __bfloat162float(tile[(px4 + 3) * 264 + c]);
    *(float4*)&out[gi] = o;
  }
}

extern "C" void kernel_launch(void* const* d_in, const int* in_sizes, int n_in,
                              void* d_out, int out_size, void* d_ws, size_t ws_size,
                              hipStream_t stream) {
  const float* m  = (const float*)d_in[0];
  const float* fb = (const float*)d_in[1];  // face 0 (back)
  const float* fu = (const float*)d_in[2];  // face 5 (up)
  const float* fd = (const float*)d_in[3];  // face 1 (down)
  const float* Wf = (const float*)d_in[4];
  const float* bf = (const float*)d_in[5];
  const float* Wm = (const float*)d_in[6];
  const float* bm = (const float*)d_in[7];
  float* out = (float*)d_out;

  char* ws = (char*)d_ws;
  // Fast path layout (Ft aliases the Xp_m region; Ft is dead before nchw writes):
  //   [0, FT_BYTES)                 : Ft, then Xp_m (XP_STRIDE <= FT_BYTES)
  //   [FT_BYTES, +XP_STRIDE)        : Xp_aux
  //   then Wtt (1179648), MauxT (67108864), maskacc (524288)
  const size_t NEED_FAST = (size_t)FT_BYTES + XP_STRIDE + 1179648 + 67108864 + 524288; // 237,438,976

  if (ws_size >= NEED_FAST) {
    __hip_bfloat16* Ft     = (__hip_bfloat16*)(ws);
    __hip_bfloat16* Xp_m   = (__hip_bfloat16*)(ws);                       // aliases Ft (after Ft dead)
    __hip_bfloat16* Xp_aux = (__hip_bfloat16*)(ws + (size_t)FT_BYTES);
    __hip_bfloat16* Wtt    = (__hip_bfloat16*)(ws + (size_t)FT_BYTES + XP_STRIDE);
    __hip_bfloat16* MauxT  = (__hip_bfloat16*)(ws + (size_t)FT_BYTES + XP_STRIDE + 1179648);
    float* maskacc         = (float*)(ws + (size_t)FT_BYTES + XP_STRIDE + 1179648 + 67108864);

    face_to_nhwc<<<3072, 256, 0, stream>>>(fb, fd, fu, Ft);
    aux_gen_v2<<<32768, 256, 0, stream>>>(Ft, Xp_aux);      // Ft dead after this
    nchw_to_pad_nhwc<<<2048, 256, 0, stream>>>(m, Xp_m);    // overwrites Ft region
    zero_borders<<<dim3(1540, 2), 128, 0, stream>>>(Xp_m, Xp_aux);
    prep_weights<<<2304, 256, 0, stream>>>(Wf, Wtt);
    zero_mask<<<512, 256, 0, stream>>>(maskacc);
    conv3x3_mfma<<<dim3(1024, 2), 512, 0, stream>>>(Xp_aux, Xp_m, Wtt, bf, Wm, MauxT, maskacc);
    final_combine<<<2048, 256, 0, stream>>>(m, MauxT, maskacc, bm, out);
  } else {
    // Fallback: round-2 layout (~195.3 MiB), planar gather aux_gen
    __hip_bfloat16* Xp_m   = (__hip_bfloat16*)(ws);
    __hip_bfloat16* Xp_aux = (__hip_bfloat16*)(ws + (size_t)XP_STRIDE);
    __hip_bfloat16* Wtt    = (__hip_bfloat16*)(ws + 2uL * XP_STRIDE);
    __hip_bfloat16* MauxT  = (__hip_bfloat16*)(ws + 2uL * XP_STRIDE + 1179648);
    float* maskacc         = (float*)(ws + 2uL * XP_STRIDE + 1179648 + 67108864);

    zero_borders<<<dim3(1540, 2), 128, 0, stream>>>(Xp_m, Xp_aux);
    zero_mask<<<512, 256, 0, stream>>>(maskacc);
    prep_weights<<<2304, 256, 0, stream>>>(Wf, Wtt);
    nchw_to_pad_nhwc<<<2048, 256, 0, stream>>>(m, Xp_m);
    aux_gen<<<2048, 256, 0, stream>>>(fb, fd, fu, Xp_aux);
    conv3x3_mfma<<<dim3(1024, 2), 512, 0, stream>>>(Xp_aux, Xp_m, Wtt, bf, Wm, MauxT, maskacc);
    final_combine<<<2048, 256, 0, stream>>>(m, MauxT, maskacc, bm, out);
  }
}

// Round 9
// 737.557 us; speedup vs baseline: 6.4290x; 1.0053x over previous
//
#include <hip/hip_runtime.h>
#include <hip/hip_bf16.h>

// Problem constants: C=256 channels, equirect H=256 x W=512, faces 256x256.
// Padded NHWC conv-input layout: Xp[(H+2)=258 rows][(W+2)=514 cols][256 ch] bf16.
#define NPIX 131072        // 256*512
#define WP   514
#define XP_BYTES 67897344  // 258*514*256*2
#define XP_STRIDE 67962880 // XP_BYTES + 64KB slack (conv halo staging over-reads up to 7KB)
#define FT_BYTES 100663296 // 3 faces * 65536 px * 256 ch * 2B (NHWC bf16)

typedef __attribute__((ext_vector_type(8))) short bf16x8;  // 8 bf16 = 4 VGPRs
typedef __attribute__((ext_vector_type(4))) float f32x4;

typedef const __attribute__((address_space(1))) void g_cvoid;
typedef __attribute__((address_space(3))) void l_void;

__device__ __forceinline__ void async16(const void* g, void* l) {
  // width-16 global->LDS DMA; LDS dest = wave-uniform base + lane*16
  __builtin_amdgcn_global_load_lds((g_cvoid*)g, (l_void*)l, 16, 0, 0);
}

// ---------------- ws state init (ws is re-poisoned 0xAA before every launch) ---
__global__ void zero_borders(__hip_bfloat16* Xm, __hip_bfloat16* Xa) {
  int i = blockIdx.x;  // 0..1539 border pixels
  __hip_bfloat16* X = blockIdx.y ? Xa : Xm;
  long ppix;
  if (i < 514)       ppix = i;                                  // top row
  else if (i < 1028) ppix = 257L * WP + (i - 514);              // bottom row
  else if (i < 1284) ppix = (long)(i - 1028 + 1) * WP;          // left col
  else               ppix = (long)(i - 1284 + 1) * WP + 513;    // right col
  ((unsigned int*)(X + ppix * 256))[threadIdx.x] = 0u;          // 128 u32 = 256 bf16
}

__global__ void zero_mask(float* maskacc) {
  maskacc[blockIdx.x * 256 + threadIdx.x] = 0.f;
}

// Wf [cout][cin][3][3] fp32 -> Wtt [(o*32 + ci>>3)][cout][ci&7] bf16
// so a B fragment (quad lq, lane ln) reads 256B-contiguous, coalesced b128.
__global__ void prep_weights(const float* __restrict__ Wf, __hip_bfloat16* __restrict__ Wtt) {
  int idx = blockIdx.x * 256 + threadIdx.x;   // 589824 total
  int cout = idx / 2304, rem = idx % 2304;
  int o = rem >> 8, ci = rem & 255;
  Wtt[(((o << 5) + (ci >> 3)) << 11) + (cout << 3) + (ci & 7)] =
      __float2bfloat16(Wf[(cout * 256 + ci) * 9 + o]);
}

// ---------------- m (NCHW fp32) -> padded NHWC bf16 ----------------------------
// G13: planar reads vectorized to float4 (4 px/lane, 16 iters).
__global__ void nchw_to_pad_nhwc(const float* __restrict__ src, __hip_bfloat16* __restrict__ Xp) {
  __shared__ __align__(16) __hip_bfloat16 tile[64 * 264];  // 64 px x 256 ch (+8 pad)
  int tid = threadIdx.x;
  int p0 = blockIdx.x * 64;
  int cw = tid >> 4;            // 0..15 channel subgroup
  int px4 = (tid & 15) << 2;    // 0,4,...,60
  for (int it = 0; it < 16; ++it) {
    int c = (it << 4) + cw;
    float4 v = *(const float4*)&src[(long)c * NPIX + p0 + px4];
    tile[(px4 + 0) * 264 + c] = __float2bfloat16(v.x);
    tile[(px4 + 1) * 264 + c] = __float2bfloat16(v.y);
    tile[(px4 + 2) * 264 + c] = __float2bfloat16(v.z);
    tile[(px4 + 3) * 264 + c] = __float2bfloat16(v.w);
  }
  __syncthreads();
  int y = p0 >> 9, x0 = p0 & 511;
  long basep = (long)(y + 1) * WP + x0 + 1;
  for (int pass = 0; pass < 8; ++pass) {
    int tpx = (pass << 3) + (tid >> 5);
    int chunk = tid & 31;
    uint4 v = *(const uint4*)&tile[tpx * 264 + (chunk << 3)];
    *(uint4*)&Xp[(basep + tpx) * 256 + (chunk << 3)] = v;
  }
}

// ---------------- faces (NCHW fp32, 3 used faces) -> NHWC bf16 -----------------
__global__ void face_to_nhwc(const float* __restrict__ fb, const float* __restrict__ fd,
                             const float* __restrict__ fu, __hip_bfloat16* __restrict__ Ft) {
  __shared__ __align__(16) __hip_bfloat16 tile[64 * 264];
  int tid = threadIdx.x;
  int face = blockIdx.x >> 10;         // 0..2 (slot: 0=b,1=d,2=u)
  int p0 = (blockIdx.x & 1023) << 6;
  const float* src = (face == 0) ? fb : (face == 1) ? fd : fu;
  int cw = tid >> 4;            // 0..15
  int px4 = (tid & 15) << 2;    // 0,4,...,60
  for (int it = 0; it < 16; ++it) {
    int c = (it << 4) + cw;
    float4 v = *(const float4*)&src[(long)c * 65536 + p0 + px4];
    tile[(px4 + 0) * 264 + c] = __float2bfloat16(v.x);
    tile[(px4 + 1) * 264 + c] = __float2bfloat16(v.y);
    tile[(px4 + 2) * 264 + c] = __float2bfloat16(v.z);
    tile[(px4 + 3) * 264 + c] = __float2bfloat16(v.w);
  }
  __syncthreads();
  long basep = ((long)face << 16) + p0;
  for (int pass = 0; pass < 8; ++pass) {
    int tpx = (pass << 3) + (tid >> 5);
    int chunk = tid & 31;
    uint4 v = *(const uint4*)&tile[tpx * 264 + (chunk << 3)];
    *(uint4*)&Ft[((basep + tpx) << 8) + (chunk << 3)] = v;
  }
}

// ---------------- cube2equi sampling v2: one wave per output pixel -------------
// Ft is NHWC bf16: sample = 512B contiguous. Lane parity = u0/u1, lane>>1 = ch octet.
__device__ __forceinline__ void bf8_fma(uint4 q, float w, float* acc) {
  unsigned x;
  x = q.x; acc[0] += w * __uint_as_float(x << 16); acc[1] += w * __uint_as_float(x & 0xffff0000u);
  x = q.y; acc[2] += w * __uint_as_float(x << 16); acc[3] += w * __uint_as_float(x & 0xffff0000u);
  x = q.z; acc[4] += w * __uint_as_float(x << 16); acc[5] += w * __uint_as_float(x & 0xffff0000u);
  x = q.w; acc[6] += w * __uint_as_float(x << 16); acc[7] += w * __uint_as_float(x & 0xffff0000u);
}

__global__ void aux_gen_v2(const __hip_bfloat16* __restrict__ Ft,
                           __hip_bfloat16* __restrict__ Xp) {
  const int lane = threadIdx.x & 63;
  const int p = (blockIdx.x << 2) + (threadIdx.x >> 6);  // one wave per pixel
  const int yy = p >> 9, xx = p & 511;

  // geometry (wave-uniform; fast HW trig: v_sin/v_cos, ~2^-20 rel err vs 0.11 tol)
  float theta = ((xx + 0.5f) / 512.f) * 6.283185307179586f - 3.141592653589793f;
  float phi   = 1.5707963267948966f - ((yy + 0.5f) / 256.f) * 3.141592653589793f;
  float st = __sinf(theta), ct = __cosf(theta);
  float sp = __sinf(phi),   cp = __cosf(phi);
  float dx = cp * st, dy = sp, dz = cp * ct;
  float ax = fabsf(dx), ay = fabsf(dy), az = fabsf(dz);
  float mx = fmaxf(fmaxf(ax, ay), az);
  float pxn = dx / mx, pyn = dy / mx, pzn = dz / mx;
  bool cz = (az >= ax) && (az >= ay);
  bool cx = (!cz) && (ax >= ay);
  int face; float a, b;
  if (cz)      { face = dz > 0.f ? 2 : 0; a = dz > 0.f ? pxn : -pxn; b = -pyn; }
  else if (cx) { face = dx > 0.f ? 4 : 3; a = dx > 0.f ? -pzn : pzn; b = -pyn; }
  else         { face = dy > 0.f ? 5 : 1; a = pxn; b = dy > 0.f ? pzn : -pzn; }
  float uu = fminf(fmaxf((a + 1.f) * 0.5f * 255.f, 0.f), 255.f);
  float vv = fminf(fmaxf((b + 1.f) * 0.5f * 255.f, 0.f), 255.f);

  const long outbase = ((long)((yy + 1) * WP + xx + 1)) << 8;
  const int c0 = (lane >> 1) << 3;     // channel octet
  const int up = lane & 1;             // 0 -> u0, 1 -> u1
  const int slot = (face == 0) ? 0 : (face == 1) ? 1 : (face == 5) ? 2 : -1;

  if (slot < 0) {                      // faces 2/3/4 are the zero 'emptyFace'
    if (!up) *(uint4*)&Xp[outbase + c0] = make_uint4(0u, 0u, 0u, 0u);
    return;
  }
  int u0 = (int)uu, v0 = (int)vv;
  int u1 = min(u0 + 1, 255), v1 = min(v0 + 1, 255);
  float wu = uu - (float)u0, wv = vv - (float)v0;
  int uc = up ? u1 : u0;
  float wA = up ? wu : (1.f - wu);
  const __hip_bfloat16* base = Ft + ((long)slot << 24);  // slot * 65536 * 256

  float acc[8] = {0.f, 0.f, 0.f, 0.f, 0.f, 0.f, 0.f, 0.f};
  uint4 q0 = *(const uint4*)&base[(((long)(v0 << 8) + uc) << 8) + c0];
  uint4 q1 = *(const uint4*)&base[(((long)(v1 << 8) + uc) << 8) + c0];
  bf8_fma(q0, (1.f - wv) * wA, acc);
  bf8_fma(q1, wv * wA, acc);
#pragma unroll
  for (int j = 0; j < 8; ++j) acc[j] += __shfl_xor(acc[j], 1);
  if (!up) {
    union { uint4 q; __hip_bfloat16 h[8]; } o;
#pragma unroll
    for (int j = 0; j < 8; ++j) o.h[j] = __float2bfloat16(acc[j]);
    *(uint4*)&Xp[outbase + c0] = o.q;
  }
}

// ---------------- cube2equi v1 (fallback when ws too small for Ft) -------------
__global__ void aux_gen(const float* __restrict__ fb, const float* __restrict__ fd,
                        const float* __restrict__ fu,
                        __hip_bfloat16* __restrict__ Xp) {
  __shared__ __align__(16) __hip_bfloat16 tile[64 * 264];
  int tid = threadIdx.x;
  int p0 = blockIdx.x * 64;
  int px = tid & 63, w = tid >> 6;

  int p = p0 + px;
  int yy = p >> 9, xx = p & 511;
  float theta = ((xx + 0.5f) / 512.f) * 6.283185307179586f - 3.141592653589793f;
  float phi   = 1.5707963267948966f - ((yy + 0.5f) / 256.f) * 3.141592653589793f;
  float st = __sinf(theta), ct = __cosf(theta);
  float sp = __sinf(phi),   cp = __cosf(phi);
  float dx = cp * st, dy = sp, dz = cp * ct;
  float ax = fabsf(dx), ay = fabsf(dy), az = fabsf(dz);
  float mx = fmaxf(fmaxf(ax, ay), az);
  float pxn = dx / mx, pyn = dy / mx, pzn = dz / mx;
  bool cz = (az >= ax) && (az >= ay);
  bool cx = (!cz) && (ax >= ay);
  int face; float a, b;
  if (cz)      { face = dz > 0.f ? 2 : 0; a = dz > 0.f ? pxn : -pxn; b = -pyn; }
  else if (cx) { face = dx > 0.f ? 4 : 3; a = dx > 0.f ? -pzn : pzn; b = -pyn; }
  else         { face = dy > 0.f ? 5 : 1; a = pxn; b = dy > 0.f ? pzn : -pzn; }
  float uu = fminf(fmaxf((a + 1.f) * 0.5f * 255.f, 0.f), 255.f);
  float vv = fminf(fmaxf((b + 1.f) * 0.5f * 255.f, 0.f), 255.f);

  const float* F = (face == 0) ? fb : (face == 1) ? fd : (face == 5) ? fu : nullptr;
  int u0 = (int)uu, v0 = (int)vv;
  int u1 = min(u0 + 1, 255), v1 = min(v0 + 1, 255);
  float wu = uu - (float)u0, wv = vv - (float)v0;
  float w00 = (1.f - wv) * (1.f - wu), w01 = (1.f - wv) * wu;
  float w10 = wv * (1.f - wu),         w11 = wv * wu;
  int i00 = v0 * 256 + u0, i01 = v0 * 256 + u1;
  int i10 = v1 * 256 + u0, i11 = v1 * 256 + u1;
  for (int k = 0; k < 64; ++k) {
    int c = (k << 2) + w;
    float val = 0.f;
    if (F) {
      const float* Fc = F + ((long)c << 16);
      val = w00 * Fc[i00] + w01 * Fc[i01] + w10 * Fc[i10] + w11 * Fc[i11];
    }
    tile[px * 264 + c] = __float2bfloat16(val);
  }
  __syncthreads();
  int y = p0 >> 9, x0g = p0 & 511;
  long basep = (long)(y + 1) * WP + x0g + 1;
  for (int pass = 0; pass < 8; ++pass) {
    int tpx = (pass << 3) + (tid >> 5);
    int chunk = tid & 31;
    uint4 v = *(const uint4*)&tile[tpx * 264 + (chunk << 3)];
    *(uint4*)&Xp[(basep + tpx) * 256 + (chunk << 3)] = v;
  }
}

// ---------------- 3x3 conv as implicit GEMM (MFMA bf16) ------------------------
// v8: BK=64 + XOR swizzle (both verified correct in round 3), register-safe.
//  - BK=64: 4 ci-slices, 8 barrier drains (was 16). Same staged bytes.
//  - Swizzle (both-sides, rule #21): LDS octet slot s of pixel p holds logical
//    octet s^(p&7); staging pre-swizzles the GLOBAL source (lane l fetches
//    octet (l&7)^(l>>3)); reads XOR with px&7. Round-3 measured ZERO bank
//    conflicts with this exact form (conflicts resolve per 16-lane quarter
//    group for b128; swizzle spreads each quarter-group over all 8 slots).
//  - REGISTER SAFETY (v6 spilled from af[2][4] double-live at the hard 128
//    unified cap): kk is a '#pragma unroll 1' runtime loop so only af[4]+bb[4]
//    are live; the XOR key sw=(ln+dxo)&7 is mi-invariant (arow,mi*16 == 0 mod 8)
//    so mi reads stay base+immediate. Spill tripwire: FETCH_SIZE must stay
//    ~124MB / WRITE ~119MB; any jump means scratch -> revert.
// grid = dim3(1024, 2): y==0 -> aux conv (stores MauxT), y==1 -> main conv.
// XCD strip swizzle: 1024 % 8 == 0 -> bijective.
__global__ __launch_bounds__(512, 4)
void conv3x3_mfma(const __hip_bfloat16* __restrict__ Xpa,
                  const __hip_bfloat16* __restrict__ Xpm,
                  const __hip_bfloat16* __restrict__ Wtt,
                  const float* __restrict__ bias,
                  const float* __restrict__ wm,
                  __hip_bfloat16* __restrict__ Out,
                  float* __restrict__ maskacc) {
  __shared__ __align__(16) __hip_bfloat16 At[4 * 80 * 64];   // 40960 B (4 rows x 80 px x 64 ch)
  const int tid = threadIdx.x;
  const int wave = tid >> 6, lane = tid & 63;
  const bool aux = (blockIdx.y == 0);
  const __hip_bfloat16* __restrict__ Xp = aux ? Xpa : Xpm;
  const float* __restrict__ wmv = aux ? wm + 256 : wm;

  const int tile = ((blockIdx.x & 7) << 7) + (blockIdx.x >> 3);  // strip -> XCD
  const int x0 = (tile >> 7) << 6;     // col strip (8 strips of 64)
  const int y0 = (tile & 127) << 1;    // row pair (rows vary fastest per XCD)
  const int wrow = wave >> 2;          // this wave's pixel row within tile (0/1)
  const int n_off = (wave & 3) << 6;   // this wave's cout quarter (0/64/128/192)
  const int lq = lane >> 4, ln = lane & 15;

  // halo staging (v5's exact verified form): wave pair (srow = wave>>1) stages
  // padded row (y0+srow); even wave 8-px chunks {0,8,16,24,32}, odd {40..72}.
  // One async16 = 8 px x 8 ci-octets (1KB); lane l -> px offset l>>3, LDS slot
  // l&7, fetching GLOBAL octet (l&7)^(l>>3). Chunk bases and srow*80 are
  // 0 mod 8, so slot s of pixel p holds logical octet s^(p&7).
  const int srow = wave >> 1;
  const long stage_row = (long)(y0 + srow) * WP + x0;
  const int q_px = lane >> 3;                     // 0..7 pixel offset in chunk
  const int q_ci = ((lane & 7) ^ q_px) << 3;      // swizzled ci offset 0..56

  f32x4 acc[4][4] = {};   // [mi (16-px col group)][ni (16-cout group)]

  for (int s = 0; s < 4; ++s) {
    const int ci0 = s << 6;
#pragma unroll
    for (int j = 0; j < 5; ++j) {
      const int chunk = ((wave & 1) ? 40 : 0) + (j << 3);
      async16(Xp + ((stage_row + chunk + q_px) << 8) + ci0 + q_ci,
              &At[(srow * 80 + chunk) << 6]);
    }
    __syncthreads();   // drains vmcnt -> staged halo visible to all waves
#pragma unroll
    for (int o = 0; o < 9; ++o) {
      const int dy = o / 3, dxo = o % 3;
      const int arow = (wrow + dy) * 80;
      const int sw = (ln + dxo) & 7;   // == px&7 for every mi (arow,mi*16 == 0 mod 8)
#pragma unroll 1
      for (int kk = 0; kk < 2; ++kk) {
        bf16x8 af[4], bb[4];
#pragma unroll
        for (int mi = 0; mi < 4; ++mi) {
          const int px = arow + mi * 16 + ln + dxo;
          af[mi] = *(const bf16x8*)&At[(px << 6) + ((((kk << 2) | lq) ^ sw) << 3)];
        }
#pragma unroll
        for (int ni = 0; ni < 4; ++ni)
          bb[ni] = *(const bf16x8*)&Wtt[(((o << 5) + (s << 3) + (kk << 2) + lq) << 11) +
                                        ((n_off + ni * 16 + ln) << 3)];
#pragma unroll
        for (int mi = 0; mi < 4; ++mi)
#pragma unroll
          for (int ni = 0; ni < 4; ++ni)
            acc[mi][ni] = __builtin_amdgcn_mfma_f32_16x16x32_bf16(af[mi], bb[ni],
                                                                  acc[mi][ni], 0, 0, 0);
      }
    }
    __syncthreads();   // protect At before next slice's staging
  }

  // epilogue: bias + relu (+store NHWC bf16 for aux) + fused mask 1x1 dot
  float bv[4], wv[4];
#pragma unroll
  for (int ni = 0; ni < 4; ++ni) {
    int cc = n_off + ni * 16 + ln;
    bv[ni] = bias[cc];
    wv[ni] = wmv[cc];
  }
  const int prow = (y0 + wrow) * 512 + x0;
#pragma unroll
  for (int mi = 0; mi < 4; ++mi) {
#pragma unroll
    for (int r = 0; r < 4; ++r) {
      int pix = prow + mi * 16 + (lq << 2) + r;   // D row = pixel col within tile
      float mp = 0.f;
#pragma unroll
      for (int ni = 0; ni < 4; ++ni) {
        float v = acc[mi][ni][r] + bv[ni];
        v = v > 0.f ? v : 0.f;
        if (aux) Out[((long)pix << 8) + (n_off + ni * 16 + ln)] = __float2bfloat16(v);
        mp += v * wv[ni];
      }
      mp += __shfl_xor(mp, 1);
      mp += __shfl_xor(mp, 2);
      mp += __shfl_xor(mp, 4);
      mp += __shfl_xor(mp, 8);
      if (ln == 0) atomicAdd(&maskacc[pix], mp);
    }
  }
}

// ---------------- final combine (sigmoid fused) --------------------------------
// out[c][p] = m[c][p] + sigmoid(maskacc[p]+bm)*M_aux_t[p][c]; aux via LDS.
// G13: m-read/out-write vectorized to float4 (4 px/lane, 16 iters).
__global__ void final_combine(const float* __restrict__ m,
                              const __hip_bfloat16* __restrict__ MauxT,
                              const float* __restrict__ maskacc,
                              const float* __restrict__ bm,
                              float* __restrict__ out) {
  __shared__ __align__(16) __hip_bfloat16 tile[64 * 264];
  __shared__ float sm[64];
  int tid = threadIdx.x;
  int p0 = blockIdx.x * 64;
  if (tid < 64) {
    float v = maskacc[p0 + tid] + bm[0];
    sm[tid] = 1.f / (1.f + expf(-v));
  }
#pragma unroll
  for (int j = 0; j < 8; ++j) {       // stage 64 px x 256 ch, coalesced uint4
    int f = j * 256 + tid;            // 0..2047
    int px = f >> 5, c8 = f & 31;
    *(uint4*)&tile[px * 264 + (c8 << 3)] =
        *(const uint4*)&MauxT[(((long)(p0 + px)) << 8) + (c8 << 3)];
  }
  __syncthreads();
  int cw = tid >> 4;            // 0..15 channel subgroup
  int px4 = (tid & 15) << 2;    // 0,4,...,60
  for (int it = 0; it < 16; ++it) {
    int c = (it << 4) + cw;
    long gi = (long)c * NPIX + p0 + px4;
    float4 mv = *(const float4*)&m[gi];
    float4 o;
    o.x = mv.x + sm[px4 + 0] * __bfloat162float(tile[(px4 + 0) * 264 + c]);
    o.y = mv.y + sm[px4 + 1] * __bfloat162float(tile[(px4 + 1) * 264 + c]);
    o.z = mv.z + sm[px4 + 2] * __bfloat162float(tile[(px4 + 2) * 264 + c]);
    o.w = mv.w + sm[px4 + 3] * __bfloat162float(tile[(px4 + 3) * 264 + c]);
    *(float4*)&out[gi] = o;
  }
}

extern "C" void kernel_launch(void* const* d_in, const int* in_sizes, int n_in,
                              void* d_out, int out_size, void* d_ws, size_t ws_size,
                              hipStream_t stream) {
  const float* m  = (const float*)d_in[0];
  const float* fb = (const float*)d_in[1];  // face 0 (back)
  const float* fu = (const float*)d_in[2];  // face 5 (up)
  const float* fd = (const float*)d_in[3];  // face 1 (down)
  const float* Wf = (const float*)d_in[4];
  const float* bf = (const float*)d_in[5];
  const float* Wm = (const float*)d_in[6];
  const float* bm = (const float*)d_in[7];
  float* out = (float*)d_out;

  char* ws = (char*)d_ws;
  // Fast path layout (Ft aliases the Xp_m region; Ft is dead before nchw writes):
  //   [0, FT_BYTES)                 : Ft, then Xp_m (XP_STRIDE <= FT_BYTES)
  //   [FT_BYTES, +XP_STRIDE)        : Xp_aux
  //   then Wtt (1179648), MauxT (67108864), maskacc (524288)
  const size_t NEED_FAST = (size_t)FT_BYTES + XP_STRIDE + 1179648 + 67108864 + 524288; // 237,438,976

  if (ws_size >= NEED_FAST) {
    __hip_bfloat16* Ft     = (__hip_bfloat16*)(ws);
    __hip_bfloat16* Xp_m   = (__hip_bfloat16*)(ws);                       // aliases Ft (after Ft dead)
    __hip_bfloat16* Xp_aux = (__hip_bfloat16*)(ws + (size_t)FT_BYTES);
    __hip_bfloat16* Wtt    = (__hip_bfloat16*)(ws + (size_t)FT_BYTES + XP_STRIDE);
    __hip_bfloat16* MauxT  = (__hip_bfloat16*)(ws + (size_t)FT_BYTES + XP_STRIDE + 1179648);
    float* maskacc         = (float*)(ws + (size_t)FT_BYTES + XP_STRIDE + 1179648 + 67108864);

    face_to_nhwc<<<3072, 256, 0, stream>>>(fb, fd, fu, Ft);
    aux_gen_v2<<<32768, 256, 0, stream>>>(Ft, Xp_aux);      // Ft dead after this
    nchw_to_pad_nhwc<<<2048, 256, 0, stream>>>(m, Xp_m);    // overwrites Ft region
    zero_borders<<<dim3(1540, 2), 128, 0, stream>>>(Xp_m, Xp_aux);
    prep_weights<<<2304, 256, 0, stream>>>(Wf, Wtt);
    zero_mask<<<512, 256, 0, stream>>>(maskacc);
    conv3x3_mfma<<<dim3(1024, 2), 512, 0, stream>>>(Xp_aux, Xp_m, Wtt, bf, Wm, MauxT, maskacc);
    final_combine<<<2048, 256, 0, stream>>>(m, MauxT, maskacc, bm, out);
  } else {
    // Fallback: round-2 layout (~195.3 MiB), planar gather aux_gen
    __hip_bfloat16* Xp_m   = (__hip_bfloat16*)(ws);
    __hip_bfloat16* Xp_aux = (__hip_bfloat16*)(ws + (size_t)XP_STRIDE);
    __hip_bfloat16* Wtt    = (__hip_bfloat16*)(ws + 2uL * XP_STRIDE);
    __hip_bfloat16* MauxT  = (__hip_bfloat16*)(ws + 2uL * XP_STRIDE + 1179648);
    float* maskacc         = (float*)(ws + 2uL * XP_STRIDE + 1179648 + 67108864);

    zero_borders<<<dim3(1540, 2), 128, 0, stream>>>(Xp_m, Xp_aux);
    zero_mask<<<512, 256, 0, stream>>>(maskacc);
    prep_weights<<<2304, 256, 0, stream>>>(Wf, Wtt);
    nchw_to_pad_nhwc<<<2048, 256, 0, stream>>>(m, Xp_m);
    aux_gen<<<2048, 256, 0, stream>>>(fb, fd, fu, Xp_aux);
    conv3x3_mfma<<<dim3(1024, 2), 512, 0, stream>>>(Xp_aux, Xp_m, Wtt, bf, Wm, MauxT, maskacc);
    final_combine<<<2048, 256, 0, stream>>>(m, MauxT, maskacc, bm, out);
  }
}